// Round 2
// baseline (962.718 us; speedup 1.0000x reference)
//
#include <hip/hip_runtime.h>
#include <hip/hip_bf16.h>
#include <stdint.h>

#define N_NODES 50000
#define N_EDGES 800000
#define HIDDEN  128
#define HEADS   4
#define HD      (HEADS*HIDDEN)   // 512

typedef __attribute__((ext_vector_type(8))) short  short8;
typedef __attribute__((ext_vector_type(4))) float  floatx4;

static __device__ __forceinline__ unsigned short bf16_bits(float f) {
    __hip_bfloat16 h = __float2bfloat16(f);
    union { __hip_bfloat16 b; unsigned short s; } u; u.b = h; return u.s;
}

// ---------------- fp32 -> bf16 cast (n must be multiple of 4) ----------------

__global__ __launch_bounds__(256) void cast_k(const float* __restrict__ in,
                                              unsigned short* __restrict__ out, int n4) {
    int i = blockIdx.x * 256 + threadIdx.x;
    if (i >= n4) return;
    float4 v = ((const float4*)in)[i];
    uint2 p;
    p.x = (unsigned)bf16_bits(v.x) | ((unsigned)bf16_bits(v.y) << 16);
    p.y = (unsigned)bf16_bits(v.z) | ((unsigned)bf16_bits(v.w) << 16);
    ((uint2*)out)[i] = p;
}

// ---------------- CSR build ----------------

__global__ __launch_bounds__(256) void hist_k(const int* __restrict__ dst,
                                              int* __restrict__ cnt, int E) {
    int e = blockIdx.x * 256 + threadIdx.x;
    if (e < E) atomicAdd(&cnt[dst[e]], 1);
}

__global__ __launch_bounds__(1024) void scan_k(const int* __restrict__ cnt,
                                               int* __restrict__ row_ptr, int n) {
    __shared__ int buf[1024];
    __shared__ int base_s;
    int t = threadIdx.x;
    if (t == 0) base_s = 0;
    __syncthreads();
    for (int start = 0; start < n; start += 1024) {
        int i = start + t;
        int v = (i < n) ? cnt[i] : 0;
        buf[t] = v;
        __syncthreads();
        for (int off = 1; off < 1024; off <<= 1) {
            int xv = (t >= off) ? buf[t - off] : 0;
            __syncthreads();
            buf[t] += xv;
            __syncthreads();
        }
        int incl = buf[t];
        int base = base_s;
        if (i < n) row_ptr[i] = base + incl - v;   // exclusive
        __syncthreads();
        if (t == 1023) base_s = base + buf[1023];
        __syncthreads();
    }
    if (t == 0) row_ptr[n] = base_s;
}

__global__ __launch_bounds__(256) void scatter_k(const int* __restrict__ src,
                                                 const int* __restrict__ dst,
                                                 const int* __restrict__ row_ptr,
                                                 int* __restrict__ fill,
                                                 int* __restrict__ src_sorted, int E) {
    int e = blockIdx.x * 256 + threadIdx.x;
    if (e >= E) return;
    int d = dst[e];
    int p = row_ptr[d] + atomicAdd(&fill[d], 1);
    src_sorted[p] = src[e];
}

// ---------------- GEMM: D[M,N] = A@B (+ A2@B2) (+ b1 + b2), K=128, bf16 MFMA ----------------
// one wave per 16x16 tile; A frag A[m=lane&15][k=quad*8+j]; B frag B[k][n=lane&15];
// C/D: col=lane&15, row=quad*4+reg.

template <typename OutT>
__global__ __launch_bounds__(256) void gemm_k(
        const __hip_bfloat16* __restrict__ A,  const __hip_bfloat16* __restrict__ B,
        const __hip_bfloat16* __restrict__ A2, const __hip_bfloat16* __restrict__ B2,
        const float* __restrict__ b1, const float* __restrict__ b2,
        OutT* __restrict__ D, int M, int N) {
    int gw   = (blockIdx.x * 256 + threadIdx.x) >> 6;
    int lane = threadIdx.x & 63;
    int ntiles = N >> 4;
    int mt = gw / ntiles;
    int nt = gw - mt * ntiles;
    if (mt * 16 >= M) return;
    int m0 = mt * 16, n0 = nt * 16;
    int r = lane & 15, quad = lane >> 4;

    floatx4 acc = {0.f, 0.f, 0.f, 0.f};
    {
        const short* Ab = (const short*)A + (size_t)(m0 + r) * HIDDEN + quad * 8;
        const short* Bb = (const short*)B + (size_t)(quad * 8) * N + n0 + r;
#pragma unroll
        for (int kk = 0; kk < HIDDEN; kk += 32) {
            short8 av = *(const short8*)(Ab + kk);
            union { short8 v; short e[8]; } bu;
#pragma unroll
            for (int j = 0; j < 8; ++j) bu.e[j] = Bb[(size_t)(kk + j) * N];
            acc = __builtin_amdgcn_mfma_f32_16x16x32_bf16(av, bu.v, acc, 0, 0, 0);
        }
    }
    if (A2) {
        const short* Ab = (const short*)A2 + (size_t)(m0 + r) * HIDDEN + quad * 8;
        const short* Bb = (const short*)B2 + (size_t)(quad * 8) * N + n0 + r;
#pragma unroll
        for (int kk = 0; kk < HIDDEN; kk += 32) {
            short8 av = *(const short8*)(Ab + kk);
            union { short8 v; short e[8]; } bu;
#pragma unroll
            for (int j = 0; j < 8; ++j) bu.e[j] = Bb[(size_t)(kk + j) * N];
            acc = __builtin_amdgcn_mfma_f32_16x16x32_bf16(av, bu.v, acc, 0, 0, 0);
        }
    }
    float bv = 0.f;
    if (b1) bv += b1[n0 + r];
    if (b2) bv += b2[n0 + r];
#pragma unroll
    for (int i = 0; i < 4; ++i) {
        int row = quad * 4 + i;
        float v = acc[i] + bv;
        if constexpr (sizeof(OutT) == 4)
            ((float*)D)[(size_t)(m0 + row) * N + n0 + r] = v;
        else
            ((__hip_bfloat16*)D)[(size_t)(m0 + row) * N + n0 + r] = __float2bfloat16(v);
    }
}

// ---------------- attention coefficients ----------------

__global__ __launch_bounds__(256) void alpha_k(const __hip_bfloat16* __restrict__ h,
                                               const float* __restrict__ att_s,
                                               const float* __restrict__ att_d,
                                               float* __restrict__ a_src,
                                               float* __restrict__ a_dst) {
    int t = blockIdx.x * 256 + threadIdx.x;
    if (t >= N_NODES * HEADS) return;
    int n = t >> 2, hd = t & 3;
    const __hip_bfloat16* hp = h + (size_t)n * HD + hd * HIDDEN;
    const float* sp = att_s + hd * HIDDEN;
    const float* dp = att_d + hd * HIDDEN;
    float s = 0.f, d = 0.f;
    for (int c = 0; c < HIDDEN; ++c) {
        float v = __bfloat162float(hp[c]);
        s += v * sp[c];
        d += v * dp[c];
    }
    a_src[t] = s;
    a_dst[t] = d;
}

// per (node,head): exp(leaky(alpha)) per incoming edge + 1/denominator.
// segment_max subtraction skipped: |alpha| <~ 10, fp32 exp is safe and
// softmax weights are shift-invariant up to rounding.
__global__ __launch_bounds__(256) void denom_k(const int* __restrict__ row_ptr,
                                               const int* __restrict__ src_sorted,
                                               const float* __restrict__ a_src,
                                               const float* __restrict__ a_dst,
                                               float* __restrict__ ew,
                                               float* __restrict__ dinv) {
    int t = blockIdx.x * 256 + threadIdx.x;
    if (t >= N_NODES * HEADS) return;
    int n = t >> 2, hd = t & 3;
    float adn = a_dst[t];
    int beg = row_ptr[n], end = row_ptr[n + 1];
    float sum = 0.f;
    for (int p = beg; p < end; ++p) {
        float a = a_src[src_sorted[p] * HEADS + hd] + adn;
        a = (a >= 0.f) ? a : 0.2f * a;
        float e = expf(a);
        ew[p * HEADS + hd] = e;
        sum += e;
    }
    dinv[t] = 1.f / (sum + 1e-16f);
}

// ---------------- message aggregation + head-mean + bias + relu ----------------
// one block per node; thread t owns channels 2t,2t+1 of the 512-wide (head,ch).

__global__ __launch_bounds__(256) void msg_k(const int* __restrict__ row_ptr,
                                             const int* __restrict__ src_sorted,
                                             const float* __restrict__ ew,
                                             const float* __restrict__ dinv,
                                             const __hip_bfloat16* __restrict__ h,
                                             const float* __restrict__ conv_b,
                                             __hip_bfloat16* __restrict__ rc) {
    int n = blockIdx.x;
    int t = threadIdx.x;
    int beg = row_ptr[n], end = row_ptr[n + 1];
    int hd = t >> 6;                       // 2t/128
    float rinv = dinv[n * HEADS + hd];     // wave-uniform
    float a0 = 0.f, a1 = 0.f;
    for (int p = beg; p < end; ++p) {
        int s = src_sorted[p];
        float w = ew[p * HEADS + hd] * rinv;
        unsigned u = *(const unsigned*)((const short*)h + (size_t)s * HD + 2 * t);
        a0 += w * __uint_as_float(u << 16);
        a1 += w * __uint_as_float(u & 0xffff0000u);
    }
    __shared__ float sh[HD];
    sh[2 * t]     = a0;
    sh[2 * t + 1] = a1;
    __syncthreads();
    if (t < HIDDEN) {
        float m = 0.25f * (sh[t] + sh[t + 128] + sh[t + 256] + sh[t + 384]) + conv_b[t];
        rc[(size_t)n * HIDDEN + t] = __float2bfloat16(m > 0.f ? m : 0.f);
    }
}

// ---------------- launcher ----------------

extern "C" void kernel_launch(void* const* d_in, const int* in_sizes, int n_in,
                              void* d_out, int out_size, void* d_ws, size_t ws_size,
                              hipStream_t stream) {
    const float* x      = (const float*)d_in[0];
    const int*   ei     = (const int*)d_in[1];
    const float* conv_w = (const float*)d_in[2];
    const float* att_s  = (const float*)d_in[3];
    const float* att_d  = (const float*)d_in[4];
    const float* conv_b = (const float*)d_in[5];
    const float* proj_w = (const float*)d_in[6];
    const float* proj_b = (const float*)d_in[7];
    const float* skip_w = (const float*)d_in[8];
    const float* skip_b = (const float*)d_in[9];
    float* out = (float*)d_out;

    char* ws = (char*)d_ws;
    size_t o = 0;
    auto alloc = [&](size_t b) { size_t c = o; o += (b + 255) & ~(size_t)255; return c; };
    __hip_bfloat16* xb16 = (__hip_bfloat16*)(ws + alloc((size_t)N_NODES * HIDDEN * 2));
    __hip_bfloat16* cwb  = (__hip_bfloat16*)(ws + alloc((size_t)2 * HIDDEN * HD * 2));
    __hip_bfloat16* pwb  = (__hip_bfloat16*)(ws + alloc((size_t)2 * HIDDEN * HIDDEN * 2));
    __hip_bfloat16* swb  = (__hip_bfloat16*)(ws + alloc((size_t)2 * HIDDEN * HIDDEN * 2));
    __hip_bfloat16* h    = (__hip_bfloat16*)(ws + alloc((size_t)N_NODES * HD * 2));
    float* a_src         = (float*)(ws + alloc((size_t)N_NODES * HEADS * 4));
    float* a_dst         = (float*)(ws + alloc((size_t)N_NODES * HEADS * 4));
    float* dinv          = (float*)(ws + alloc((size_t)N_NODES * HEADS * 4));
    int* row_ptr         = (int*)(ws + alloc((size_t)(N_NODES + 1) * 4));
    int* cnt             = (int*)(ws + alloc((size_t)N_NODES * 4));
    int* fill            = (int*)(ws + alloc((size_t)N_NODES * 4));
    int* src_s           = (int*)(ws + alloc((size_t)N_EDGES * 4));
    float* ew            = (float*)(ws + alloc((size_t)N_EDGES * HEADS * 4));
    __hip_bfloat16* rc   = (__hip_bfloat16*)(ws + alloc((size_t)N_NODES * HIDDEN * 2));
    __hip_bfloat16* xb   = (__hip_bfloat16*)(ws + alloc((size_t)N_NODES * HIDDEN * 2));

    const int* srcp = ei;
    const int* dstp = ei + N_EDGES;

    hipMemsetAsync(cnt, 0, (size_t)N_NODES * 4, stream);
    hipMemsetAsync(fill, 0, (size_t)N_NODES * 4, stream);

    cast_k<<<(N_NODES * HIDDEN / 4 + 255) / 256, 256, 0, stream>>>(x, (unsigned short*)xb16, N_NODES * HIDDEN / 4);
    cast_k<<<(2 * HIDDEN * HD / 4 + 255) / 256, 256, 0, stream>>>(conv_w, (unsigned short*)cwb, 2 * HIDDEN * HD / 4);
    cast_k<<<(2 * HIDDEN * HIDDEN / 4 + 255) / 256, 256, 0, stream>>>(proj_w, (unsigned short*)pwb, 2 * HIDDEN * HIDDEN / 4);
    cast_k<<<(2 * HIDDEN * HIDDEN / 4 + 255) / 256, 256, 0, stream>>>(skip_w, (unsigned short*)swb, 2 * HIDDEN * HIDDEN / 4);

    hist_k<<<(N_EDGES + 255) / 256, 256, 0, stream>>>(dstp, cnt, N_EDGES);
    scan_k<<<1, 1024, 0, stream>>>(cnt, row_ptr, N_NODES);
    scatter_k<<<(N_EDGES + 255) / 256, 256, 0, stream>>>(srcp, dstp, row_ptr, fill, src_s, N_EDGES);

    const int mtiles = (N_NODES + 15) / 16;  // 3125
    const __hip_bfloat16* xc = xb16;
    for (int l = 0; l < 2; ++l) {
        {   // h = xc @ conv_w[l]   [50000,128]x[128,512] -> bf16
            int waves = mtiles * (HD / 16);
            gemm_k<__hip_bfloat16><<<(waves + 3) / 4, 256, 0, stream>>>(
                xc, cwb + (size_t)l * HIDDEN * HD,
                nullptr, nullptr, nullptr, nullptr, h, N_NODES, HD);
        }
        alpha_k<<<(N_NODES * HEADS + 255) / 256, 256, 0, stream>>>(
            h, att_s + l * HD, att_d + l * HD, a_src, a_dst);
        denom_k<<<(N_NODES * HEADS + 255) / 256, 256, 0, stream>>>(
            row_ptr, src_s, a_src, a_dst, ew, dinv);
        msg_k<<<N_NODES, 256, 0, stream>>>(
            row_ptr, src_s, ew, dinv, h, conv_b + l * HIDDEN, rc);
        {   // out_l = relu(conv)@proj_w + xc@skip_w + proj_b + skip_b
            int waves = mtiles * (HIDDEN / 16);
            if (l == 0) {
                gemm_k<__hip_bfloat16><<<(waves + 3) / 4, 256, 0, stream>>>(
                    rc, pwb + (size_t)l * HIDDEN * HIDDEN,
                    xc, swb + (size_t)l * HIDDEN * HIDDEN,
                    proj_b + l * HIDDEN, skip_b + l * HIDDEN, xb, N_NODES, HIDDEN);
            } else {
                gemm_k<float><<<(waves + 3) / 4, 256, 0, stream>>>(
                    rc, pwb + (size_t)l * HIDDEN * HIDDEN,
                    xc, swb + (size_t)l * HIDDEN * HIDDEN,
                    proj_b + l * HIDDEN, skip_b + l * HIDDEN, out, N_NODES, HIDDEN);
            }
        }
        xc = xb;
    }
}

// Round 4
// 546.012 us; speedup vs baseline: 1.7632x; 1.7632x over previous
//
#include <hip/hip_runtime.h>
#include <hip/hip_bf16.h>
#include <stdint.h>

#define N_NODES 50000
#define N_EDGES 800000
#define HIDDEN  128
#define HEADS   4
#define HD      (HEADS*HIDDEN)   // 512

typedef __attribute__((ext_vector_type(8))) short  short8;
typedef __attribute__((ext_vector_type(4))) float  floatx4;

static __device__ __forceinline__ unsigned short bf16_bits(float f) {
    __hip_bfloat16 h = __float2bfloat16(f);
    union { __hip_bfloat16 b; unsigned short s; } u; u.b = h; return u.s;
}

// ---------------- fp32 -> bf16 cast (x), n4 = elems/4 ----------------

__global__ __launch_bounds__(256) void cast_k(const float* __restrict__ in,
                                              unsigned short* __restrict__ out, int n4) {
    int i = blockIdx.x * 256 + threadIdx.x;
    if (i >= n4) return;
    float4 v = ((const float4*)in)[i];
    uint2 p;
    p.x = (unsigned)bf16_bits(v.x) | ((unsigned)bf16_bits(v.y) << 16);
    p.y = (unsigned)bf16_bits(v.z) | ((unsigned)bf16_bits(v.w) << 16);
    ((uint2*)out)[i] = p;
}

// ---------------- weight cast + MFMA-fragment swizzle ----------------
// dst[o], o -> j=o&7, r=(o>>3)&15, q=(o>>7)&3, rest=o>>9, nt=rest%(N/16), kc=rest/(N/16)
// value = B[kc*32 + q*8 + j][nt*16 + r]   (B is K=128 x N row-major fp32)

__global__ __launch_bounds__(256) void wswz_k(const float* __restrict__ B,
                                              unsigned short* __restrict__ Bs, int N) {
    int o = blockIdx.x * 256 + threadIdx.x;
    if (o >= 128 * N) return;
    int j = o & 7, r = (o >> 3) & 15, q = (o >> 7) & 3;
    int rest = o >> 9, ntn = N >> 4;
    int nt = rest % ntn, kc = rest / ntn;
    int row = kc * 32 + q * 8 + j, col = nt * 16 + r;
    Bs[o] = bf16_bits(B[(size_t)row * N + col]);
}

// ---------------- CSR build ----------------

__global__ __launch_bounds__(256) void hist_k(const int* __restrict__ dst,
                                              int* __restrict__ cnt, int E) {
    int e = blockIdx.x * 256 + threadIdx.x;
    if (e < E) atomicAdd(&cnt[dst[e]], 1);
}

// device-wide exclusive scan: per-block scan -> scan of block sums -> add
__global__ __launch_bounds__(1024) void scan1_k(const int* __restrict__ cnt,
                                                int* __restrict__ row_ptr,
                                                int* __restrict__ bsum, int n) {
    __shared__ int buf[1024];
    int t = threadIdx.x, i = blockIdx.x * 1024 + t;
    int v = (i < n) ? cnt[i] : 0;
    buf[t] = v;
    __syncthreads();
    for (int off = 1; off < 1024; off <<= 1) {
        int xv = (t >= off) ? buf[t - off] : 0;
        __syncthreads();
        buf[t] += xv;
        __syncthreads();
    }
    if (i < n) row_ptr[i] = buf[t] - v;          // block-local exclusive
    if (t == 1023) bsum[blockIdx.x] = buf[1023];
}

__global__ void scan2_k(int* __restrict__ bsum, int nb) {
    if (threadIdx.x == 0) {
        int acc = 0;
        for (int i = 0; i < nb; ++i) { int v = bsum[i]; bsum[i] = acc; acc += v; }
    }
}

__global__ __launch_bounds__(1024) void scan3_k(int* __restrict__ row_ptr,
                                                const int* __restrict__ bsum, int n, int E) {
    int i = blockIdx.x * 1024 + threadIdx.x;
    if (i < n) row_ptr[i] += bsum[blockIdx.x];
    if (i == 0) row_ptr[n] = E;
}

__global__ __launch_bounds__(256) void scatter_k(const int* __restrict__ src,
                                                 const int* __restrict__ dst,
                                                 const int* __restrict__ row_ptr,
                                                 int* __restrict__ fill,
                                                 int* __restrict__ src_sorted, int E) {
    int e = blockIdx.x * 256 + threadIdx.x;
    if (e >= E) return;
    int d = dst[e];
    int p = row_ptr[d] + atomicAdd(&fill[d], 1);
    src_sorted[p] = src[e];
}

// ---------------- conv GEMM: h = A@conv_w (bf16 MFMA), fused alpha epilogue ----------------
// one wave per (mtile16, head); Ntile=128 (== one head). Bs is fragment-swizzled.

__global__ __launch_bounds__(256) void gemmc_k(
        const __hip_bfloat16* __restrict__ A,      // M x 128 bf16
        const unsigned short* __restrict__ Bs,     // swizzled 128x512
        const float* __restrict__ att_s, const float* __restrict__ att_d,  // [4][128]
        __hip_bfloat16* __restrict__ h,
        float* __restrict__ a_src, float* __restrict__ a_dst, int M) {
    int wv = (blockIdx.x * 256 + threadIdx.x) >> 6;
    int lane = threadIdx.x & 63;
    int head = wv & 3;
    int mt = wv >> 2;
    if (mt * 16 >= M) return;
    int m0 = mt * 16, r = lane & 15, q = lane >> 4;

    floatx4 acc[8];
#pragma unroll
    for (int i = 0; i < 8; ++i) acc[i] = (floatx4){0.f, 0.f, 0.f, 0.f};

    const short* Ab = (const short*)A + (size_t)(m0 + r) * HIDDEN + q * 8;
#pragma unroll
    for (int kc = 0; kc < 4; ++kc) {
        short8 av = *(const short8*)(Ab + kc * 32);
#pragma unroll
        for (int ntl = 0; ntl < 8; ++ntl) {
            const short* bp = (const short*)Bs +
                (((size_t)(kc * 32 + head * 8 + ntl) * 4 + q) * 128 + r * 8);
            short8 bv = *(const short8*)bp;
            acc[ntl] = __builtin_amdgcn_mfma_f32_16x16x32_bf16(av, bv, acc[ntl], 0, 0, 0);
        }
    }
    // store h (bf16)
#pragma unroll
    for (int ntl = 0; ntl < 8; ++ntl)
#pragma unroll
        for (int i = 0; i < 4; ++i) {
            int row = m0 + q * 4 + i;
            h[(size_t)row * HD + head * HIDDEN + ntl * 16 + r] = __float2bfloat16(acc[ntl][i]);
        }
    // fused alpha: per-row dot with att vectors (fp32 acc), reduce over 16 lanes
    float sA[4] = {0.f, 0.f, 0.f, 0.f}, sD[4] = {0.f, 0.f, 0.f, 0.f};
#pragma unroll
    for (int ntl = 0; ntl < 8; ++ntl) {
        float as = att_s[head * HIDDEN + ntl * 16 + r];
        float ad = att_d[head * HIDDEN + ntl * 16 + r];
#pragma unroll
        for (int i = 0; i < 4; ++i) { sA[i] += acc[ntl][i] * as; sD[i] += acc[ntl][i] * ad; }
    }
#pragma unroll
    for (int d = 1; d < 16; d <<= 1)
#pragma unroll
        for (int i = 0; i < 4; ++i) {
            sA[i] += __shfl_xor(sA[i], d);
            sD[i] += __shfl_xor(sD[i], d);
        }
    if (r == 0)
#pragma unroll
        for (int i = 0; i < 4; ++i) {
            int row = m0 + q * 4 + i;
            a_src[row * HEADS + head] = sA[i];
            a_dst[row * HEADS + head] = sD[i];
        }
}

// ---------------- proj+skip dual GEMM: D = A@Bs + A2@Bs2 + b1 + b2 ----------------
// one wave per mtile16; N=128.

template <typename OutT>
__global__ __launch_bounds__(256) void gemmp_k(
        const __hip_bfloat16* __restrict__ A,  const unsigned short* __restrict__ Bs,
        const __hip_bfloat16* __restrict__ A2, const unsigned short* __restrict__ Bs2,
        const float* __restrict__ b1, const float* __restrict__ b2,
        OutT* __restrict__ D, int M) {
    int wv = (blockIdx.x * 256 + threadIdx.x) >> 6;
    int lane = threadIdx.x & 63;
    if (wv * 16 >= M) return;
    int m0 = wv * 16, r = lane & 15, q = lane >> 4;

    floatx4 acc[8];
#pragma unroll
    for (int i = 0; i < 8; ++i) acc[i] = (floatx4){0.f, 0.f, 0.f, 0.f};

    const short* Ab = (const short*)A + (size_t)(m0 + r) * HIDDEN + q * 8;
#pragma unroll
    for (int kc = 0; kc < 4; ++kc) {
        short8 av = *(const short8*)(Ab + kc * 32);
#pragma unroll
        for (int ntl = 0; ntl < 8; ++ntl) {
            short8 bv = *(const short8*)((const short*)Bs +
                (((size_t)(kc * 8 + ntl) * 4 + q) * 128 + r * 8));
            acc[ntl] = __builtin_amdgcn_mfma_f32_16x16x32_bf16(av, bv, acc[ntl], 0, 0, 0);
        }
    }
    const short* Ab2 = (const short*)A2 + (size_t)(m0 + r) * HIDDEN + q * 8;
#pragma unroll
    for (int kc = 0; kc < 4; ++kc) {
        short8 av = *(const short8*)(Ab2 + kc * 32);
#pragma unroll
        for (int ntl = 0; ntl < 8; ++ntl) {
            short8 bv = *(const short8*)((const short*)Bs2 +
                (((size_t)(kc * 8 + ntl) * 4 + q) * 128 + r * 8));
            acc[ntl] = __builtin_amdgcn_mfma_f32_16x16x32_bf16(av, bv, acc[ntl], 0, 0, 0);
        }
    }
#pragma unroll
    for (int ntl = 0; ntl < 8; ++ntl) {
        int col = ntl * 16 + r;
        float bias = b1[col] + b2[col];
#pragma unroll
        for (int i = 0; i < 4; ++i) {
            int row = m0 + q * 4 + i;
            float v = acc[ntl][i] + bias;
            if constexpr (sizeof(OutT) == 4)
                ((float*)D)[(size_t)row * HIDDEN + col] = v;
            else
                ((__hip_bfloat16*)D)[(size_t)row * HIDDEN + col] = __float2bfloat16(v);
        }
    }
}

// ---------------- softmax denominators ----------------

__global__ __launch_bounds__(256) void denom_k(const int* __restrict__ row_ptr,
                                               const int* __restrict__ src_sorted,
                                               const float* __restrict__ a_src,
                                               const float* __restrict__ a_dst,
                                               float* __restrict__ ew,
                                               float* __restrict__ dinv) {
    int t = blockIdx.x * 256 + threadIdx.x;
    if (t >= N_NODES * HEADS) return;
    int n = t >> 2, hd = t & 3;
    float adn = a_dst[t];
    int beg = row_ptr[n], end = row_ptr[n + 1];
    float sum = 0.f;
    for (int p = beg; p < end; ++p) {
        float a = a_src[src_sorted[p] * HEADS + hd] + adn;
        a = (a >= 0.f) ? a : 0.2f * a;
        float e = expf(a);
        ew[p * HEADS + hd] = e;
        sum += e;
    }
    dinv[t] = 1.f / (sum + 1e-16f);
}

// ---------------- message aggregation: one wave per node ----------------
// lane owns 8 channels (16B) of the 512-wide row; head = lane>>4.
// edges staged 32 at a time via coalesced loads + shfl broadcast.

static __device__ __forceinline__ void acc8(float* acc, uint4 u, float wt) {
    acc[0] += wt * __uint_as_float(u.x << 16);
    acc[1] += wt * __uint_as_float(u.x & 0xffff0000u);
    acc[2] += wt * __uint_as_float(u.y << 16);
    acc[3] += wt * __uint_as_float(u.y & 0xffff0000u);
    acc[4] += wt * __uint_as_float(u.z << 16);
    acc[5] += wt * __uint_as_float(u.z & 0xffff0000u);
    acc[6] += wt * __uint_as_float(u.w << 16);
    acc[7] += wt * __uint_as_float(u.w & 0xffff0000u);
}

__global__ __launch_bounds__(256) void msg_k(const int* __restrict__ row_ptr,
                                             const int* __restrict__ src_sorted,
                                             const float* __restrict__ ew,
                                             const float* __restrict__ dinv,
                                             const __hip_bfloat16* __restrict__ h,
                                             const float* __restrict__ conv_b,
                                             __hip_bfloat16* __restrict__ rc) {
    int wave = threadIdx.x >> 6;
    int lane = threadIdx.x & 63;
    int n = blockIdx.x * 4 + wave;
    if (n >= N_NODES) return;
    int head = lane >> 4;
    float rinv = dinv[n * HEADS + head];
    int beg = row_ptr[n], end = row_ptr[n + 1];
    const uint4* hq = (const uint4*)h;

    float acc[8] = {0.f, 0.f, 0.f, 0.f, 0.f, 0.f, 0.f, 0.f};
    for (int base = beg; base < end; base += 32) {
        int m = min(32, end - base);
        int sv    = (lane < m)          ? src_sorted[base + lane]  : 0;
        float w0s = (lane < 4 * m)      ? ew[base * 4 + lane]      : 0.f;
        float w1s = (lane + 64 < 4 * m) ? ew[base * 4 + 64 + lane] : 0.f;
        int j = 0;
        for (; j + 2 <= m; j += 2) {
            int s0 = __shfl(sv, j), s1 = __shfl(sv, j + 1);
            uint4 u0 = hq[(size_t)s0 * 64 + lane];
            uint4 u1 = hq[(size_t)s1 * 64 + lane];
            float wt0 = ((j     < 16) ? __shfl(w0s, 4 * j + head)
                                      : __shfl(w1s, 4 * j - 64 + head)) * rinv;
            float wt1 = ((j + 1 < 16) ? __shfl(w0s, 4 * j + 4 + head)
                                      : __shfl(w1s, 4 * j - 60 + head)) * rinv;
            acc8(acc, u0, wt0);
            acc8(acc, u1, wt1);
        }
        if (j < m) {
            int s0 = __shfl(sv, j);
            uint4 u0 = hq[(size_t)s0 * 64 + lane];
            float wt0 = ((j < 16) ? __shfl(w0s, 4 * j + head)
                                  : __shfl(w1s, 4 * j - 64 + head)) * rinv;
            acc8(acc, u0, wt0);
        }
    }
    // head mean: lanes l, l^16, l^32, l^48 hold same within-head channels
#pragma unroll
    for (int k = 0; k < 8; ++k) {
        acc[k] += __shfl_xor(acc[k], 16);
        acc[k] += __shfl_xor(acc[k], 32);
    }
    if (lane < 16) {
        union { uint4 v; unsigned short us[8]; } o;
#pragma unroll
        for (int k = 0; k < 8; ++k) {
            float mres = 0.25f * acc[k] + conv_b[8 * lane + k];
            o.us[k] = bf16_bits(mres > 0.f ? mres : 0.f);
        }
        ((uint4*)rc)[(size_t)n * 16 + lane] = o.v;
    }
}

// ---------------- launcher ----------------

extern "C" void kernel_launch(void* const* d_in, const int* in_sizes, int n_in,
                              void* d_out, int out_size, void* d_ws, size_t ws_size,
                              hipStream_t stream) {
    const float* x      = (const float*)d_in[0];
    const int*   ei     = (const int*)d_in[1];
    const float* conv_w = (const float*)d_in[2];
    const float* att_s  = (const float*)d_in[3];
    const float* att_d  = (const float*)d_in[4];
    const float* conv_b = (const float*)d_in[5];
    const float* proj_w = (const float*)d_in[6];
    const float* proj_b = (const float*)d_in[7];
    const float* skip_w = (const float*)d_in[8];
    const float* skip_b = (const float*)d_in[9];
    float* out = (float*)d_out;

    char* ws = (char*)d_ws;
    size_t o = 0;
    auto alloc = [&](size_t b) { size_t c = o; o += (b + 255) & ~(size_t)255; return c; };
    __hip_bfloat16* xb16 = (__hip_bfloat16*)(ws + alloc((size_t)N_NODES * HIDDEN * 2));
    unsigned short* cwb  = (unsigned short*)(ws + alloc((size_t)2 * HIDDEN * HD * 2));
    unsigned short* pwb  = (unsigned short*)(ws + alloc((size_t)2 * HIDDEN * HIDDEN * 2));
    unsigned short* swb  = (unsigned short*)(ws + alloc((size_t)2 * HIDDEN * HIDDEN * 2));
    __hip_bfloat16* h    = (__hip_bfloat16*)(ws + alloc((size_t)N_NODES * HD * 2));
    float* a_src         = (float*)(ws + alloc((size_t)N_NODES * HEADS * 4));
    float* a_dst         = (float*)(ws + alloc((size_t)N_NODES * HEADS * 4));
    float* dinv          = (float*)(ws + alloc((size_t)N_NODES * HEADS * 4));
    int* row_ptr         = (int*)(ws + alloc((size_t)(N_NODES + 1) * 4));
    int* cnt             = (int*)(ws + alloc((size_t)N_NODES * 4));
    int* fill            = (int*)(ws + alloc((size_t)N_NODES * 4));
    int* src_s           = (int*)(ws + alloc((size_t)N_EDGES * 4));
    float* ew            = (float*)(ws + alloc((size_t)N_EDGES * HEADS * 4));
    __hip_bfloat16* rc   = (__hip_bfloat16*)(ws + alloc((size_t)N_NODES * HIDDEN * 2));
    __hip_bfloat16* xb   = (__hip_bfloat16*)(ws + alloc((size_t)N_NODES * HIDDEN * 2));
    int* bsum            = (int*)(ws + alloc(64 * 4));

    const int* srcp = ei;
    const int* dstp = ei + N_EDGES;

    (void)hipMemsetAsync(cnt, 0, (size_t)N_NODES * 4, stream);
    (void)hipMemsetAsync(fill, 0, (size_t)N_NODES * 4, stream);

    cast_k<<<(N_NODES * HIDDEN / 4 + 255) / 256, 256, 0, stream>>>(
        x, (unsigned short*)xb16, N_NODES * HIDDEN / 4);
    for (int l = 0; l < 2; ++l) {
        wswz_k<<<(HIDDEN * HD + 255) / 256, 256, 0, stream>>>(
            conv_w + (size_t)l * HIDDEN * HD, cwb + (size_t)l * HIDDEN * HD, HD);
        wswz_k<<<(HIDDEN * HIDDEN + 255) / 256, 256, 0, stream>>>(
            proj_w + (size_t)l * HIDDEN * HIDDEN, pwb + (size_t)l * HIDDEN * HIDDEN, HIDDEN);
        wswz_k<<<(HIDDEN * HIDDEN + 255) / 256, 256, 0, stream>>>(
            skip_w + (size_t)l * HIDDEN * HIDDEN, swb + (size_t)l * HIDDEN * HIDDEN, HIDDEN);
    }

    hist_k<<<(N_EDGES + 255) / 256, 256, 0, stream>>>(dstp, cnt, N_EDGES);
    const int nb = (N_NODES + 1023) / 1024;  // 49
    scan1_k<<<nb, 1024, 0, stream>>>(cnt, row_ptr, bsum, N_NODES);
    scan2_k<<<1, 64, 0, stream>>>(bsum, nb);
    scan3_k<<<nb, 1024, 0, stream>>>(row_ptr, bsum, N_NODES, N_EDGES);
    scatter_k<<<(N_EDGES + 255) / 256, 256, 0, stream>>>(srcp, dstp, row_ptr, fill, src_s, N_EDGES);

    const __hip_bfloat16* xc = xb16;
    for (int l = 0; l < 2; ++l) {
        {   // h = xc @ conv_w[l] + fused alpha
            int waves = (N_NODES / 16) * HEADS;       // 12500
            gemmc_k<<<waves / 4, 256, 0, stream>>>(
                xc, cwb + (size_t)l * HIDDEN * HD,
                att_s + l * HD, att_d + l * HD, h, a_src, a_dst, N_NODES);
        }
        denom_k<<<(N_NODES * HEADS + 255) / 256, 256, 0, stream>>>(
            row_ptr, src_s, a_src, a_dst, ew, dinv);
        msg_k<<<N_NODES / 4, 256, 0, stream>>>(
            row_ptr, src_s, ew, dinv, h, conv_b + l * HIDDEN, rc);
        {   // out_l = relu(conv)@proj_w + xc@skip_w + biases
            int blocks = (N_NODES / 16 + 3) / 4;      // 782
            if (l == 0)
                gemmp_k<__hip_bfloat16><<<blocks, 256, 0, stream>>>(
                    rc, pwb + (size_t)l * HIDDEN * HIDDEN,
                    xc, swb + (size_t)l * HIDDEN * HIDDEN,
                    proj_b + l * HIDDEN, skip_b + l * HIDDEN, xb, N_NODES);
            else
                gemmp_k<float><<<blocks, 256, 0, stream>>>(
                    rc, pwb + (size_t)l * HIDDEN * HIDDEN,
                    xc, swb + (size_t)l * HIDDEN * HIDDEN,
                    proj_b + l * HIDDEN, skip_b + l * HIDDEN, out, N_NODES);
        }
        xc = xb;
    }
}

// Round 5
// 526.642 us; speedup vs baseline: 1.8280x; 1.0368x over previous
//
#include <hip/hip_runtime.h>
#include <hip/hip_bf16.h>
#include <stdint.h>

#define N_NODES 50000
#define N_EDGES 800000
#define HIDDEN  128
#define HEADS   4
#define HD      (HEADS*HIDDEN)   // 512

typedef __attribute__((ext_vector_type(8))) short  short8;
typedef __attribute__((ext_vector_type(4))) float  floatx4;

static __device__ __forceinline__ unsigned short bf16_bits(float f) {
    __hip_bfloat16 h = __float2bfloat16(f);
    union { __hip_bfloat16 b; unsigned short s; } u; u.b = h; return u.s;
}

// leaky_relu(a, 0.2) == max(a, 0.2a); then fast exp
static __device__ __forceinline__ float lexp(float a) {
    return __expf(fmaxf(a, 0.2f * a));
}

// ---------------- fp32 -> bf16 cast (x), n4 = elems/4 ----------------

__global__ __launch_bounds__(256) void cast_k(const float* __restrict__ in,
                                              unsigned short* __restrict__ out, int n4) {
    int i = blockIdx.x * 256 + threadIdx.x;
    if (i >= n4) return;
    float4 v = ((const float4*)in)[i];
    uint2 p;
    p.x = (unsigned)bf16_bits(v.x) | ((unsigned)bf16_bits(v.y) << 16);
    p.y = (unsigned)bf16_bits(v.z) | ((unsigned)bf16_bits(v.w) << 16);
    ((uint2*)out)[i] = p;
}

// ---------------- all weights: cast + MFMA-fragment swizzle, one launch ----------------
// off -> j=off&7, r=(off>>3)&15, q=(off>>7)&3, rest=off>>9, nt=rest%(N/16), kc=rest/(N/16)
// value = B[kc*32 + q*8 + j][nt*16 + r]

__global__ __launch_bounds__(256) void wswz_all(
        const float* __restrict__ conv_w, const float* __restrict__ proj_w,
        const float* __restrict__ skip_w,
        unsigned short* __restrict__ cwb, unsigned short* __restrict__ pwb,
        unsigned short* __restrict__ swb) {
    int o = blockIdx.x * 256 + threadIdx.x;
    const float* B; unsigned short* D; int off, N;
    if (o < 131072)      { B = conv_w + (o >> 16) * 65536; D = cwb + (o >> 16) * 65536; off = o & 65535; N = 512; }
    else if (o < 163840) { int t = o - 131072; B = proj_w + (t >> 14) * 16384; D = pwb + (t >> 14) * 16384; off = t & 16383; N = 128; }
    else if (o < 196608) { int t = o - 163840; B = skip_w + (t >> 14) * 16384; D = swb + (t >> 14) * 16384; off = t & 16383; N = 128; }
    else return;
    int j = off & 7, r = (off >> 3) & 15, q = (off >> 7) & 3;
    int rest = off >> 9, ntn = N >> 4;
    int nt = rest % ntn, kc = rest / ntn;
    D[off] = bf16_bits(B[(size_t)(kc * 32 + q * 8 + j) * N + nt * 16 + r]);
}

// ---------------- CSR build ----------------

__global__ __launch_bounds__(256) void hist_k(const int* __restrict__ dst,
                                              int* __restrict__ cnt, int E) {
    int e = blockIdx.x * 256 + threadIdx.x;
    if (e < E) atomicAdd(&cnt[dst[e]], 1);
}

__global__ __launch_bounds__(1024) void scan1_k(const int* __restrict__ cnt,
                                                int* __restrict__ row_ptr,
                                                int* __restrict__ bsum, int n) {
    __shared__ int buf[1024];
    int t = threadIdx.x, i = blockIdx.x * 1024 + t;
    int v = (i < n) ? cnt[i] : 0;
    buf[t] = v;
    __syncthreads();
    for (int off = 1; off < 1024; off <<= 1) {
        int xv = (t >= off) ? buf[t - off] : 0;
        __syncthreads();
        buf[t] += xv;
        __syncthreads();
    }
    if (i < n) row_ptr[i] = buf[t] - v;
    if (t == 1023) bsum[blockIdx.x] = buf[1023];
}

__global__ void scan2_k(int* __restrict__ bsum, int nb) {
    if (threadIdx.x == 0) {
        int acc = 0;
        for (int i = 0; i < nb; ++i) { int v = bsum[i]; bsum[i] = acc; acc += v; }
    }
}

__global__ __launch_bounds__(1024) void scan3_k(int* __restrict__ row_ptr,
                                                const int* __restrict__ bsum, int n, int E) {
    int i = blockIdx.x * 1024 + threadIdx.x;
    if (i < n) row_ptr[i] += bsum[blockIdx.x];
    if (i == 0) row_ptr[n] = E;
}

__global__ __launch_bounds__(256) void scatter_k(const int* __restrict__ src,
                                                 const int* __restrict__ dst,
                                                 const int* __restrict__ row_ptr,
                                                 int* __restrict__ fill,
                                                 int* __restrict__ src_sorted, int E) {
    int e = blockIdx.x * 256 + threadIdx.x;
    if (e >= E) return;
    int d = dst[e];
    int p = row_ptr[d] + atomicAdd(&fill[d], 1);
    src_sorted[p] = src[e];
}

// ---------------- conv GEMM: h = A@conv_w, 32-row tiles, fused alpha ----------------
// one wave per (mtile32, head); B fragments reused across both 16-row halves.

__global__ __launch_bounds__(256) void gemmc_k(
        const __hip_bfloat16* __restrict__ A,      // M x 128 bf16
        const unsigned short* __restrict__ Bs,     // swizzled 128x512
        const float* __restrict__ att_s, const float* __restrict__ att_d,
        __hip_bfloat16* __restrict__ h,
        float* __restrict__ a_src, float* __restrict__ a_dst, int M) {
    int wv = (blockIdx.x * 256 + threadIdx.x) >> 6;
    int lane = threadIdx.x & 63;
    int head = wv & 3;
    int mt = wv >> 2;
    if (mt * 32 >= M) return;
    int m0 = mt * 32, r = lane & 15, q = lane >> 4;
    bool v2 = (m0 + 16 < M);

    floatx4 acc0[8], acc1[8];
#pragma unroll
    for (int i = 0; i < 8; ++i) { acc0[i] = (floatx4){0,0,0,0}; acc1[i] = (floatx4){0,0,0,0}; }

    const short* Ab0 = (const short*)A + (size_t)(m0 + r) * HIDDEN + q * 8;
    const short* Ab1 = (const short*)A + (size_t)(v2 ? m0 + 16 + r : m0 + r) * HIDDEN + q * 8;
#pragma unroll
    for (int kc = 0; kc < 4; ++kc) {
        short8 av0 = *(const short8*)(Ab0 + kc * 32);
        short8 av1 = *(const short8*)(Ab1 + kc * 32);
#pragma unroll
        for (int ntl = 0; ntl < 8; ++ntl) {
            short8 bv = *(const short8*)((const short*)Bs +
                (((size_t)(kc * 32 + head * 8 + ntl) * 4 + q) * 128 + r * 8));
            acc0[ntl] = __builtin_amdgcn_mfma_f32_16x16x32_bf16(av0, bv, acc0[ntl], 0, 0, 0);
            acc1[ntl] = __builtin_amdgcn_mfma_f32_16x16x32_bf16(av1, bv, acc1[ntl], 0, 0, 0);
        }
    }
    // store h
#pragma unroll
    for (int ntl = 0; ntl < 8; ++ntl)
#pragma unroll
        for (int i = 0; i < 4; ++i) {
            int col = head * HIDDEN + ntl * 16 + r;
            h[(size_t)(m0 + q * 4 + i) * HD + col] = __float2bfloat16(acc0[ntl][i]);
            if (v2)
                h[(size_t)(m0 + 16 + q * 4 + i) * HD + col] = __float2bfloat16(acc1[ntl][i]);
        }
    // fused alpha
    float sA0[4] = {0,0,0,0}, sD0[4] = {0,0,0,0}, sA1[4] = {0,0,0,0}, sD1[4] = {0,0,0,0};
#pragma unroll
    for (int ntl = 0; ntl < 8; ++ntl) {
        float as = att_s[head * HIDDEN + ntl * 16 + r];
        float ad = att_d[head * HIDDEN + ntl * 16 + r];
#pragma unroll
        for (int i = 0; i < 4; ++i) {
            sA0[i] += acc0[ntl][i] * as; sD0[i] += acc0[ntl][i] * ad;
            sA1[i] += acc1[ntl][i] * as; sD1[i] += acc1[ntl][i] * ad;
        }
    }
#pragma unroll
    for (int d = 1; d < 16; d <<= 1)
#pragma unroll
        for (int i = 0; i < 4; ++i) {
            sA0[i] += __shfl_xor(sA0[i], d); sD0[i] += __shfl_xor(sD0[i], d);
            sA1[i] += __shfl_xor(sA1[i], d); sD1[i] += __shfl_xor(sD1[i], d);
        }
    if (r == 0)
#pragma unroll
        for (int i = 0; i < 4; ++i) {
            int row0 = m0 + q * 4 + i;
            a_src[row0 * HEADS + head] = sA0[i];
            a_dst[row0 * HEADS + head] = sD0[i];
            if (v2) {
                a_src[(row0 + 16) * HEADS + head] = sA1[i];
                a_dst[(row0 + 16) * HEADS + head] = sD1[i];
            }
        }
}

// ---------------- proj+skip dual GEMM, 32-row tiles ----------------

template <typename OutT>
__global__ __launch_bounds__(256) void gemmp_k(
        const __hip_bfloat16* __restrict__ A,  const unsigned short* __restrict__ Bs,
        const __hip_bfloat16* __restrict__ A2, const unsigned short* __restrict__ Bs2,
        const float* __restrict__ b1, const float* __restrict__ b2,
        OutT* __restrict__ D, int M) {
    int wv = (blockIdx.x * 256 + threadIdx.x) >> 6;
    int lane = threadIdx.x & 63;
    if (wv * 32 >= M) return;
    int m0 = wv * 32, r = lane & 15, q = lane >> 4;
    bool v2 = (m0 + 16 < M);

    floatx4 acc0[8], acc1[8];
#pragma unroll
    for (int i = 0; i < 8; ++i) { acc0[i] = (floatx4){0,0,0,0}; acc1[i] = (floatx4){0,0,0,0}; }

    {
        const short* Ab0 = (const short*)A + (size_t)(m0 + r) * HIDDEN + q * 8;
        const short* Ab1 = (const short*)A + (size_t)(v2 ? m0 + 16 + r : m0 + r) * HIDDEN + q * 8;
#pragma unroll
        for (int kc = 0; kc < 4; ++kc) {
            short8 av0 = *(const short8*)(Ab0 + kc * 32);
            short8 av1 = *(const short8*)(Ab1 + kc * 32);
#pragma unroll
            for (int ntl = 0; ntl < 8; ++ntl) {
                short8 bv = *(const short8*)((const short*)Bs +
                    (((size_t)(kc * 8 + ntl) * 4 + q) * 128 + r * 8));
                acc0[ntl] = __builtin_amdgcn_mfma_f32_16x16x32_bf16(av0, bv, acc0[ntl], 0, 0, 0);
                acc1[ntl] = __builtin_amdgcn_mfma_f32_16x16x32_bf16(av1, bv, acc1[ntl], 0, 0, 0);
            }
        }
    }
    {
        const short* Ab0 = (const short*)A2 + (size_t)(m0 + r) * HIDDEN + q * 8;
        const short* Ab1 = (const short*)A2 + (size_t)(v2 ? m0 + 16 + r : m0 + r) * HIDDEN + q * 8;
#pragma unroll
        for (int kc = 0; kc < 4; ++kc) {
            short8 av0 = *(const short8*)(Ab0 + kc * 32);
            short8 av1 = *(const short8*)(Ab1 + kc * 32);
#pragma unroll
            for (int ntl = 0; ntl < 8; ++ntl) {
                short8 bv = *(const short8*)((const short*)Bs2 +
                    (((size_t)(kc * 8 + ntl) * 4 + q) * 128 + r * 8));
                acc0[ntl] = __builtin_amdgcn_mfma_f32_16x16x32_bf16(av0, bv, acc0[ntl], 0, 0, 0);
                acc1[ntl] = __builtin_amdgcn_mfma_f32_16x16x32_bf16(av1, bv, acc1[ntl], 0, 0, 0);
            }
        }
    }
#pragma unroll
    for (int ntl = 0; ntl < 8; ++ntl) {
        int col = ntl * 16 + r;
        float bias = b1[col] + b2[col];
#pragma unroll
        for (int i = 0; i < 4; ++i) {
            int row = m0 + q * 4 + i;
            float v0 = acc0[ntl][i] + bias;
            float v1 = acc1[ntl][i] + bias;
            if constexpr (sizeof(OutT) == 4) {
                ((float*)D)[(size_t)row * HIDDEN + col] = v0;
                if (v2) ((float*)D)[(size_t)(row + 16) * HIDDEN + col] = v1;
            } else {
                ((__hip_bfloat16*)D)[(size_t)row * HIDDEN + col] = __float2bfloat16(v0);
                if (v2) ((__hip_bfloat16*)D)[(size_t)(row + 16) * HIDDEN + col] = __float2bfloat16(v1);
            }
        }
    }
}

// ---------------- fused softmax + aggregation: one wave per node ----------------
// msg = (sum_e e_i * h[src_i]) / (sum_e e_i);  e_i = exp(leaky(a_src[src]+a_dst[n]))
// lane owns 8 channels (16B) of the 512-wide row; head = lane>>4.

static __device__ __forceinline__ void acc8(float* acc, uint4 u, float wt) {
    acc[0] += wt * __uint_as_float(u.x << 16);
    acc[1] += wt * __uint_as_float(u.x & 0xffff0000u);
    acc[2] += wt * __uint_as_float(u.y << 16);
    acc[3] += wt * __uint_as_float(u.y & 0xffff0000u);
    acc[4] += wt * __uint_as_float(u.z << 16);
    acc[5] += wt * __uint_as_float(u.z & 0xffff0000u);
    acc[6] += wt * __uint_as_float(u.w << 16);
    acc[7] += wt * __uint_as_float(u.w & 0xffff0000u);
}

__global__ __launch_bounds__(256) void msg_k(const int* __restrict__ row_ptr,
                                             const int* __restrict__ src_sorted,
                                             const float* __restrict__ a_src,
                                             const float* __restrict__ a_dst,
                                             const __hip_bfloat16* __restrict__ h,
                                             const float* __restrict__ conv_b,
                                             __hip_bfloat16* __restrict__ rc) {
    int wave = threadIdx.x >> 6;
    int lane = threadIdx.x & 63;
    int n = blockIdx.x * 4 + wave;
    if (n >= N_NODES) return;
    int head = lane >> 4;
    float adn = a_dst[n * HEADS + head];
    int beg = row_ptr[n], end = row_ptr[n + 1];
    const uint4* hq = (const uint4*)h;

    float acc[8] = {0.f, 0.f, 0.f, 0.f, 0.f, 0.f, 0.f, 0.f};
    float esum = 0.f;
    for (int base = beg; base < end; base += 32) {
        int m = min(32, end - base);
        int sv = (lane < m) ? src_sorted[base + lane] : 0;
        int j = 0;
        for (; j + 4 <= m; j += 4) {
            int s0 = __shfl(sv, j),     s1 = __shfl(sv, j + 1);
            int s2 = __shfl(sv, j + 2), s3 = __shfl(sv, j + 3);
            uint4 u0 = hq[(size_t)s0 * 64 + lane];
            uint4 u1 = hq[(size_t)s1 * 64 + lane];
            uint4 u2 = hq[(size_t)s2 * 64 + lane];
            uint4 u3 = hq[(size_t)s3 * 64 + lane];
            float e0 = lexp(a_src[s0 * 4 + head] + adn);
            float e1 = lexp(a_src[s1 * 4 + head] + adn);
            float e2 = lexp(a_src[s2 * 4 + head] + adn);
            float e3 = lexp(a_src[s3 * 4 + head] + adn);
            acc8(acc, u0, e0);
            acc8(acc, u1, e1);
            acc8(acc, u2, e2);
            acc8(acc, u3, e3);
            esum += (e0 + e1) + (e2 + e3);
        }
        for (; j < m; ++j) {
            int s0 = __shfl(sv, j);
            uint4 u0 = hq[(size_t)s0 * 64 + lane];
            float e0 = lexp(a_src[s0 * 4 + head] + adn);
            acc8(acc, u0, e0);
            esum += e0;
        }
    }
    float rinv = 1.f / (esum + 1e-16f);
#pragma unroll
    for (int k = 0; k < 8; ++k) acc[k] *= rinv;
    // head mean: lanes l, l^16, l^32, l^48 hold same within-head channels
#pragma unroll
    for (int k = 0; k < 8; ++k) {
        acc[k] += __shfl_xor(acc[k], 16);
        acc[k] += __shfl_xor(acc[k], 32);
    }
    if (lane < 16) {
        union { uint4 v; unsigned short us[8]; } o;
#pragma unroll
        for (int k = 0; k < 8; ++k) {
            float mres = 0.25f * acc[k] + conv_b[8 * lane + k];
            o.us[k] = bf16_bits(mres > 0.f ? mres : 0.f);
        }
        ((uint4*)rc)[(size_t)n * 16 + lane] = o.v;
    }
}

// ---------------- launcher ----------------

extern "C" void kernel_launch(void* const* d_in, const int* in_sizes, int n_in,
                              void* d_out, int out_size, void* d_ws, size_t ws_size,
                              hipStream_t stream) {
    const float* x      = (const float*)d_in[0];
    const int*   ei     = (const int*)d_in[1];
    const float* conv_w = (const float*)d_in[2];
    const float* att_s  = (const float*)d_in[3];
    const float* att_d  = (const float*)d_in[4];
    const float* conv_b = (const float*)d_in[5];
    const float* proj_w = (const float*)d_in[6];
    const float* proj_b = (const float*)d_in[7];
    const float* skip_w = (const float*)d_in[8];
    const float* skip_b = (const float*)d_in[9];
    float* out = (float*)d_out;

    char* ws = (char*)d_ws;
    size_t o = 0;
    auto alloc = [&](size_t b) { size_t c = o; o += (b + 255) & ~(size_t)255; return c; };
    __hip_bfloat16* xb16 = (__hip_bfloat16*)(ws + alloc((size_t)N_NODES * HIDDEN * 2));
    unsigned short* cwb  = (unsigned short*)(ws + alloc((size_t)2 * HIDDEN * HD * 2));
    unsigned short* pwb  = (unsigned short*)(ws + alloc((size_t)2 * HIDDEN * HIDDEN * 2));
    unsigned short* swb  = (unsigned short*)(ws + alloc((size_t)2 * HIDDEN * HIDDEN * 2));
    __hip_bfloat16* h    = (__hip_bfloat16*)(ws + alloc((size_t)N_NODES * HD * 2));
    float* a_src         = (float*)(ws + alloc((size_t)N_NODES * HEADS * 4));
    float* a_dst         = (float*)(ws + alloc((size_t)N_NODES * HEADS * 4));
    int* row_ptr         = (int*)(ws + alloc((size_t)(N_NODES + 1) * 4));
    int* cnt             = (int*)(ws + alloc((size_t)N_NODES * 4));
    int* fill            = (int*)(ws + alloc((size_t)N_NODES * 4));
    int* src_s           = (int*)(ws + alloc((size_t)N_EDGES * 4));
    __hip_bfloat16* rc   = (__hip_bfloat16*)(ws + alloc((size_t)N_NODES * HIDDEN * 2));
    __hip_bfloat16* xb   = (__hip_bfloat16*)(ws + alloc((size_t)N_NODES * HIDDEN * 2));
    int* bsum            = (int*)(ws + alloc(64 * 4));

    const int* srcp = ei;
    const int* dstp = ei + N_EDGES;

    (void)hipMemsetAsync(cnt, 0, (size_t)N_NODES * 4, stream);
    (void)hipMemsetAsync(fill, 0, (size_t)N_NODES * 4, stream);

    cast_k<<<(N_NODES * HIDDEN / 4 + 255) / 256, 256, 0, stream>>>(
        x, (unsigned short*)xb16, N_NODES * HIDDEN / 4);
    wswz_all<<<768, 256, 0, stream>>>(conv_w, proj_w, skip_w, cwb, pwb, swb);

    hist_k<<<(N_EDGES + 255) / 256, 256, 0, stream>>>(dstp, cnt, N_EDGES);
    const int nb = (N_NODES + 1023) / 1024;  // 49
    scan1_k<<<nb, 1024, 0, stream>>>(cnt, row_ptr, bsum, N_NODES);
    scan2_k<<<1, 64, 0, stream>>>(bsum, nb);
    scan3_k<<<nb, 1024, 0, stream>>>(row_ptr, bsum, N_NODES, N_EDGES);
    scatter_k<<<(N_EDGES + 255) / 256, 256, 0, stream>>>(srcp, dstp, row_ptr, fill, src_s, N_EDGES);

    const int mt32 = (N_NODES + 31) / 32;     // 1563
    const __hip_bfloat16* xc = xb16;
    for (int l = 0; l < 2; ++l) {
        {   // h = xc @ conv_w[l] + fused alpha
            int waves = mt32 * HEADS;          // 6252
            gemmc_k<<<(waves + 3) / 4, 256, 0, stream>>>(
                xc, cwb + (size_t)l * HIDDEN * HD,
                att_s + l * HD, att_d + l * HD, h, a_src, a_dst, N_NODES);
        }
        msg_k<<<(N_NODES + 3) / 4, 256, 0, stream>>>(
            row_ptr, src_s, a_src, a_dst, h, conv_b + l * HIDDEN, rc);
        {   // out_l = relu(conv)@proj_w + xc@skip_w + biases
            int blocks = (mt32 + 3) / 4;       // 391
            if (l == 0)
                gemmp_k<__hip_bfloat16><<<blocks, 256, 0, stream>>>(
                    rc, pwb + (size_t)l * HIDDEN * HIDDEN,
                    xc, swb + (size_t)l * HIDDEN * HIDDEN,
                    proj_b + l * HIDDEN, skip_b + l * HIDDEN, xb, N_NODES);
            else
                gemmp_k<float><<<blocks, 256, 0, stream>>>(
                    rc, pwb + (size_t)l * HIDDEN * HIDDEN,
                    xc, swb + (size_t)l * HIDDEN * HIDDEN,
                    proj_b + l * HIDDEN, skip_b + l * HIDDEN, out, N_NODES);
        }
        xc = xb;
    }
}

// Round 6
// 477.913 us; speedup vs baseline: 2.0144x; 1.1020x over previous
//
#include <hip/hip_runtime.h>
#include <hip/hip_bf16.h>
#include <stdint.h>

#define N_NODES 50000
#define N_EDGES 800000
#define HIDDEN  128
#define HEADS   4
#define HD      (HEADS*HIDDEN)   // 512

typedef __attribute__((ext_vector_type(8))) short  short8;
typedef __attribute__((ext_vector_type(4))) float  floatx4;

static __device__ __forceinline__ unsigned short bf16_bits(float f) {
    __hip_bfloat16 h = __float2bfloat16(f);
    union { __hip_bfloat16 b; unsigned short s; } u; u.b = h; return u.s;
}

// leaky_relu(a, 0.2) == max(a, 0.2a); then fast exp
static __device__ __forceinline__ float lexp(float a) {
    return __expf(fmaxf(a, 0.2f * a));
}

// ---------------- fp32 -> bf16 cast (x), n4 = elems/4 ----------------

__global__ __launch_bounds__(256) void cast_k(const float* __restrict__ in,
                                              unsigned short* __restrict__ out, int n4) {
    int i = blockIdx.x * 256 + threadIdx.x;
    if (i >= n4) return;
    float4 v = ((const float4*)in)[i];
    uint2 p;
    p.x = (unsigned)bf16_bits(v.x) | ((unsigned)bf16_bits(v.y) << 16);
    p.y = (unsigned)bf16_bits(v.z) | ((unsigned)bf16_bits(v.w) << 16);
    ((uint2*)out)[i] = p;
}

// ---------------- all weights: cast + MFMA-fragment swizzle, one launch ----------------
// fragment element (kc,nt,q,r,j) at offset ((kc*(N/16)+nt)*4+q)*128 + r*8 + j
// natural source row kr = kc*32+q*8+j, col = nt*16+r.
// proj_w rows are PERMUTED (kr -> (kr&7)*16 + (kr>>3)) to compensate the
// permuted channel layout of rc (written by msg_k as [r][ntl]).

__global__ __launch_bounds__(256) void wswz_all(
        const float* __restrict__ conv_w, const float* __restrict__ proj_w,
        const float* __restrict__ skip_w,
        unsigned short* __restrict__ cwb, unsigned short* __restrict__ pwb,
        unsigned short* __restrict__ swb) {
    int o = blockIdx.x * 256 + threadIdx.x;
    const float* B; unsigned short* D; int off, N; bool perm = false;
    if (o < 131072)      { B = conv_w + (o >> 16) * 65536; D = cwb + (o >> 16) * 65536; off = o & 65535; N = 512; }
    else if (o < 163840) { int t = o - 131072; B = proj_w + (t >> 14) * 16384; D = pwb + (t >> 14) * 16384; off = t & 16383; N = 128; perm = true; }
    else if (o < 196608) { int t = o - 163840; B = skip_w + (t >> 14) * 16384; D = swb + (t >> 14) * 16384; off = t & 16383; N = 128; }
    else return;
    int j = off & 7, r = (off >> 3) & 15, q = (off >> 7) & 3;
    int rest = off >> 9, ntn = N >> 4;
    int nt = rest % ntn, kc = rest / ntn;
    int kr = kc * 32 + q * 8 + j;
    int row = perm ? ((kr & 7) * 16 + (kr >> 3)) : kr;
    D[off] = bf16_bits(B[(size_t)row * N + nt * 16 + r]);
}

// ---------------- CSR build ----------------

__global__ __launch_bounds__(256) void hist_k(const int* __restrict__ dst,
                                              int* __restrict__ cnt, int E) {
    int e = blockIdx.x * 256 + threadIdx.x;
    if (e < E) atomicAdd(&cnt[dst[e]], 1);
}

__global__ __launch_bounds__(1024) void scan1_k(const int* __restrict__ cnt,
                                                int* __restrict__ row_ptr,
                                                int* __restrict__ bsum, int n) {
    __shared__ int buf[1024];
    int t = threadIdx.x, i = blockIdx.x * 1024 + t;
    int v = (i < n) ? cnt[i] : 0;
    buf[t] = v;
    __syncthreads();
    for (int off = 1; off < 1024; off <<= 1) {
        int xv = (t >= off) ? buf[t - off] : 0;
        __syncthreads();
        buf[t] += xv;
        __syncthreads();
    }
    if (i < n) row_ptr[i] = buf[t] - v;
    if (t == 1023) bsum[blockIdx.x] = buf[1023];
}

__global__ void scan2_k(int* __restrict__ bsum, int nb) {
    if (threadIdx.x == 0) {
        int acc = 0;
        for (int i = 0; i < nb; ++i) { int v = bsum[i]; bsum[i] = acc; acc += v; }
    }
}

__global__ __launch_bounds__(1024) void scan3_k(int* __restrict__ row_ptr,
                                                const int* __restrict__ bsum, int n, int E) {
    int i = blockIdx.x * 1024 + threadIdx.x;
    if (i < n) row_ptr[i] += bsum[blockIdx.x];
    if (i == 0) row_ptr[n] = E;
}

__global__ __launch_bounds__(256) void scatter_k(const int* __restrict__ src,
                                                 const int* __restrict__ dst,
                                                 const int* __restrict__ row_ptr,
                                                 int* __restrict__ fill,
                                                 int* __restrict__ src_sorted, int E) {
    int e = blockIdx.x * 256 + threadIdx.x;
    if (e >= E) return;
    int d = dst[e];
    int p = row_ptr[d] + atomicAdd(&fill[d], 1);
    src_sorted[p] = src[e];
}

// ---------------- conv GEMM: h = A@conv_w, B-in-registers, grid-stride M ----------------
// wave = head; B panel (32 frags, 128 VGPR) loaded once; fused alpha epilogue.
// h row layout: [head][r][ntl] (natural channel ntl*16+r at position r*8+ntl).

__global__ __launch_bounds__(256, 2) void gemmc_k(
        const __hip_bfloat16* __restrict__ A,      // M x 128 bf16 (natural)
        const unsigned short* __restrict__ Bs,     // swizzled 128x512
        const float* __restrict__ att_s, const float* __restrict__ att_d,
        __hip_bfloat16* __restrict__ h,
        float* __restrict__ a_src, float* __restrict__ a_dst, int mtiles) {
    int head = threadIdx.x >> 6;
    int lane = threadIdx.x & 63;
    int r = lane & 15, q = lane >> 4;

    short8 Bf[4][8];
#pragma unroll
    for (int kc = 0; kc < 4; ++kc)
#pragma unroll
        for (int ntl = 0; ntl < 8; ++ntl)
            Bf[kc][ntl] = *(const short8*)((const short*)Bs +
                (((size_t)(kc * 32 + head * 8 + ntl) * 4 + q) * 128 + r * 8));

    float as_r[8], ad_r[8];
#pragma unroll
    for (int ntl = 0; ntl < 8; ++ntl) {
        as_r[ntl] = att_s[head * HIDDEN + ntl * 16 + r];
        ad_r[ntl] = att_d[head * HIDDEN + ntl * 16 + r];
    }

    for (int mt = blockIdx.x; mt < mtiles; mt += gridDim.x) {
        int m0 = mt * 16;
        const short* Ab = (const short*)A + (size_t)(m0 + r) * HIDDEN + q * 8;
        short8 av[4];
#pragma unroll
        for (int kc = 0; kc < 4; ++kc) av[kc] = *(const short8*)(Ab + kc * 32);

        floatx4 acc[8];
#pragma unroll
        for (int i = 0; i < 8; ++i) acc[i] = (floatx4){0.f, 0.f, 0.f, 0.f};
#pragma unroll
        for (int kc = 0; kc < 4; ++kc)
#pragma unroll
            for (int ntl = 0; ntl < 8; ++ntl)
                acc[ntl] = __builtin_amdgcn_mfma_f32_16x16x32_bf16(av[kc], Bf[kc][ntl], acc[ntl], 0, 0, 0);

        // store h: row q*4+i, 16B per row per lane, layout [head][r][ntl]
#pragma unroll
        for (int i = 0; i < 4; ++i) {
            union { uint4 v; unsigned short us[8]; } o;
#pragma unroll
            for (int ntl = 0; ntl < 8; ++ntl) o.us[ntl] = bf16_bits(acc[ntl][i]);
            *(uint4*)(h + (size_t)(m0 + q * 4 + i) * HD + head * HIDDEN + r * 8) = o.v;
        }
        // fused alpha
        float sA[4] = {0, 0, 0, 0}, sD[4] = {0, 0, 0, 0};
#pragma unroll
        for (int ntl = 0; ntl < 8; ++ntl)
#pragma unroll
            for (int i = 0; i < 4; ++i) {
                sA[i] += acc[ntl][i] * as_r[ntl];
                sD[i] += acc[ntl][i] * ad_r[ntl];
            }
#pragma unroll
        for (int d = 1; d < 16; d <<= 1)
#pragma unroll
            for (int i = 0; i < 4; ++i) {
                sA[i] += __shfl_xor(sA[i], d);
                sD[i] += __shfl_xor(sD[i], d);
            }
        if (r == 0)
#pragma unroll
            for (int i = 0; i < 4; ++i) {
                int row = m0 + q * 4 + i;
                a_src[row * HEADS + head] = sA[i];
                a_dst[row * HEADS + head] = sD[i];
            }
    }
}

// ---------------- proj+skip dual GEMM: B-in-registers, grid-stride M ----------------
// wave&1 = N-half (64 cols); waves {0,1} and {2,3} take alternating M-tiles.
// A (=rc) is channel-permuted; compensated by pwb's row permutation. A2 natural.

template <typename OutT>
__global__ __launch_bounds__(256, 2) void gemmp_k(
        const __hip_bfloat16* __restrict__ A,  const unsigned short* __restrict__ Bs,
        const __hip_bfloat16* __restrict__ A2, const unsigned short* __restrict__ Bs2,
        const float* __restrict__ b1, const float* __restrict__ b2,
        OutT* __restrict__ D, int mtiles) {
    int wave = threadIdx.x >> 6;
    int lane = threadIdx.x & 63;
    int r = lane & 15, q = lane >> 4;
    int nh = wave & 1;

    short8 Bf[4][4], Bf2[4][4];
#pragma unroll
    for (int kc = 0; kc < 4; ++kc)
#pragma unroll
        for (int ntl = 0; ntl < 4; ++ntl) {
            size_t off = (((size_t)(kc * 8 + nh * 4 + ntl) * 4 + q) * 128 + r * 8);
            Bf[kc][ntl]  = *(const short8*)((const short*)Bs  + off);
            Bf2[kc][ntl] = *(const short8*)((const short*)Bs2 + off);
        }
    float bias[4];
#pragma unroll
    for (int ntl = 0; ntl < 4; ++ntl) {
        int col = nh * 64 + ntl * 16 + r;
        bias[ntl] = b1[col] + b2[col];
    }

    for (int mt = blockIdx.x * 2 + (wave >> 1); mt < mtiles; mt += gridDim.x * 2) {
        int m0 = mt * 16;
        const short* Ab  = (const short*)A  + (size_t)(m0 + r) * HIDDEN + q * 8;
        const short* Ab2 = (const short*)A2 + (size_t)(m0 + r) * HIDDEN + q * 8;
        short8 av[4], av2[4];
#pragma unroll
        for (int kc = 0; kc < 4; ++kc) {
            av[kc]  = *(const short8*)(Ab  + kc * 32);
            av2[kc] = *(const short8*)(Ab2 + kc * 32);
        }
        floatx4 acc[4];
#pragma unroll
        for (int i = 0; i < 4; ++i) acc[i] = (floatx4){0.f, 0.f, 0.f, 0.f};
#pragma unroll
        for (int kc = 0; kc < 4; ++kc)
#pragma unroll
            for (int ntl = 0; ntl < 4; ++ntl) {
                acc[ntl] = __builtin_amdgcn_mfma_f32_16x16x32_bf16(av[kc],  Bf[kc][ntl],  acc[ntl], 0, 0, 0);
                acc[ntl] = __builtin_amdgcn_mfma_f32_16x16x32_bf16(av2[kc], Bf2[kc][ntl], acc[ntl], 0, 0, 0);
            }
#pragma unroll
        for (int ntl = 0; ntl < 4; ++ntl) {
            int col = nh * 64 + ntl * 16 + r;
#pragma unroll
            for (int i = 0; i < 4; ++i) {
                int row = m0 + q * 4 + i;
                float v = acc[ntl][i] + bias[ntl];
                if constexpr (sizeof(OutT) == 4)
                    ((float*)D)[(size_t)row * HIDDEN + col] = v;
                else
                    ((__hip_bfloat16*)D)[(size_t)row * HIDDEN + col] = __float2bfloat16(v);
            }
        }
    }
}

// ---------------- fused softmax + aggregation: one wave per node (UNCHANGED loop) ----------------

static __device__ __forceinline__ void acc8(float* acc, uint4 u, float wt) {
    acc[0] += wt * __uint_as_float(u.x << 16);
    acc[1] += wt * __uint_as_float(u.x & 0xffff0000u);
    acc[2] += wt * __uint_as_float(u.y << 16);
    acc[3] += wt * __uint_as_float(u.y & 0xffff0000u);
    acc[4] += wt * __uint_as_float(u.z << 16);
    acc[5] += wt * __uint_as_float(u.z & 0xffff0000u);
    acc[6] += wt * __uint_as_float(u.w << 16);
    acc[7] += wt * __uint_as_float(u.w & 0xffff0000u);
}

__global__ __launch_bounds__(256) void msg_k(const int* __restrict__ row_ptr,
                                             const int* __restrict__ src_sorted,
                                             const float* __restrict__ a_src,
                                             const float* __restrict__ a_dst,
                                             const __hip_bfloat16* __restrict__ h,
                                             const float* __restrict__ conv_b,
                                             __hip_bfloat16* __restrict__ rc) {
    int wave = threadIdx.x >> 6;
    int lane = threadIdx.x & 63;
    int n = blockIdx.x * 4 + wave;
    if (n >= N_NODES) return;
    int head = lane >> 4;
    float adn = a_dst[n * HEADS + head];
    int beg = row_ptr[n], end = row_ptr[n + 1];
    const uint4* hq = (const uint4*)h;

    float acc[8] = {0.f, 0.f, 0.f, 0.f, 0.f, 0.f, 0.f, 0.f};
    float esum = 0.f;
    for (int base = beg; base < end; base += 32) {
        int m = min(32, end - base);
        int sv = (lane < m) ? src_sorted[base + lane] : 0;
        int j = 0;
        for (; j + 4 <= m; j += 4) {
            int s0 = __shfl(sv, j),     s1 = __shfl(sv, j + 1);
            int s2 = __shfl(sv, j + 2), s3 = __shfl(sv, j + 3);
            uint4 u0 = hq[(size_t)s0 * 64 + lane];
            uint4 u1 = hq[(size_t)s1 * 64 + lane];
            uint4 u2 = hq[(size_t)s2 * 64 + lane];
            uint4 u3 = hq[(size_t)s3 * 64 + lane];
            float e0 = lexp(a_src[s0 * 4 + head] + adn);
            float e1 = lexp(a_src[s1 * 4 + head] + adn);
            float e2 = lexp(a_src[s2 * 4 + head] + adn);
            float e3 = lexp(a_src[s3 * 4 + head] + adn);
            acc8(acc, u0, e0);
            acc8(acc, u1, e1);
            acc8(acc, u2, e2);
            acc8(acc, u3, e3);
            esum += (e0 + e1) + (e2 + e3);
        }
        for (; j < m; ++j) {
            int s0 = __shfl(sv, j);
            uint4 u0 = hq[(size_t)s0 * 64 + lane];
            float e0 = lexp(a_src[s0 * 4 + head] + adn);
            acc8(acc, u0, e0);
            esum += e0;
        }
    }
    float rinv = 1.f / (esum + 1e-16f);
#pragma unroll
    for (int k = 0; k < 8; ++k) acc[k] *= rinv;
#pragma unroll
    for (int k = 0; k < 8; ++k) {
        acc[k] += __shfl_xor(acc[k], 16);
        acc[k] += __shfl_xor(acc[k], 32);
    }
    if (lane < 16) {
        // lane holds natural channels {k*16+lane}; rc written permuted [r][ntl]
        union { uint4 v; unsigned short us[8]; } o;
#pragma unroll
        for (int k = 0; k < 8; ++k) {
            float mres = 0.25f * acc[k] + conv_b[k * 16 + lane];
            o.us[k] = bf16_bits(mres > 0.f ? mres : 0.f);
        }
        ((uint4*)rc)[(size_t)n * 16 + lane] = o.v;
    }
}

// ---------------- launcher ----------------

extern "C" void kernel_launch(void* const* d_in, const int* in_sizes, int n_in,
                              void* d_out, int out_size, void* d_ws, size_t ws_size,
                              hipStream_t stream) {
    const float* x      = (const float*)d_in[0];
    const int*   ei     = (const int*)d_in[1];
    const float* conv_w = (const float*)d_in[2];
    const float* att_s  = (const float*)d_in[3];
    const float* att_d  = (const float*)d_in[4];
    const float* conv_b = (const float*)d_in[5];
    const float* proj_w = (const float*)d_in[6];
    const float* proj_b = (const float*)d_in[7];
    const float* skip_w = (const float*)d_in[8];
    const float* skip_b = (const float*)d_in[9];
    float* out = (float*)d_out;

    char* ws = (char*)d_ws;
    size_t o = 0;
    auto alloc = [&](size_t b) { size_t c = o; o += (b + 255) & ~(size_t)255; return c; };
    __hip_bfloat16* xb16 = (__hip_bfloat16*)(ws + alloc((size_t)N_NODES * HIDDEN * 2));
    unsigned short* cwb  = (unsigned short*)(ws + alloc((size_t)2 * HIDDEN * HD * 2));
    unsigned short* pwb  = (unsigned short*)(ws + alloc((size_t)2 * HIDDEN * HIDDEN * 2));
    unsigned short* swb  = (unsigned short*)(ws + alloc((size_t)2 * HIDDEN * HIDDEN * 2));
    __hip_bfloat16* h    = (__hip_bfloat16*)(ws + alloc((size_t)N_NODES * HD * 2));
    float* a_src         = (float*)(ws + alloc((size_t)N_NODES * HEADS * 4));
    float* a_dst         = (float*)(ws + alloc((size_t)N_NODES * HEADS * 4));
    int* row_ptr         = (int*)(ws + alloc((size_t)(N_NODES + 1) * 4));
    int* cnt             = (int*)(ws + alloc((size_t)N_NODES * 4));
    int* fill            = (int*)(ws + alloc((size_t)N_NODES * 4));
    int* src_s           = (int*)(ws + alloc((size_t)N_EDGES * 4));
    __hip_bfloat16* rc   = (__hip_bfloat16*)(ws + alloc((size_t)N_NODES * HIDDEN * 2));
    __hip_bfloat16* xb   = (__hip_bfloat16*)(ws + alloc((size_t)N_NODES * HIDDEN * 2));
    int* bsum            = (int*)(ws + alloc(64 * 4));

    const int* srcp = ei;
    const int* dstp = ei + N_EDGES;

    (void)hipMemsetAsync(cnt, 0, (size_t)N_NODES * 4, stream);
    (void)hipMemsetAsync(fill, 0, (size_t)N_NODES * 4, stream);

    cast_k<<<(N_NODES * HIDDEN / 4 + 255) / 256, 256, 0, stream>>>(
        x, (unsigned short*)xb16, N_NODES * HIDDEN / 4);
    wswz_all<<<768, 256, 0, stream>>>(conv_w, proj_w, skip_w, cwb, pwb, swb);

    hist_k<<<(N_EDGES + 255) / 256, 256, 0, stream>>>(dstp, cnt, N_EDGES);
    const int nb = (N_NODES + 1023) / 1024;  // 49
    scan1_k<<<nb, 1024, 0, stream>>>(cnt, row_ptr, bsum, N_NODES);
    scan2_k<<<1, 64, 0, stream>>>(bsum, nb);
    scan3_k<<<nb, 1024, 0, stream>>>(row_ptr, bsum, N_NODES, N_EDGES);
    scatter_k<<<(N_EDGES + 255) / 256, 256, 0, stream>>>(srcp, dstp, row_ptr, fill, src_s, N_EDGES);

    const int mtiles = N_NODES / 16;          // 3125 (exact)
    const __hip_bfloat16* xc = xb16;
    for (int l = 0; l < 2; ++l) {
        gemmc_k<<<512, 256, 0, stream>>>(
            xc, cwb + (size_t)l * HIDDEN * HD,
            att_s + l * HD, att_d + l * HD, h, a_src, a_dst, mtiles);
        msg_k<<<(N_NODES + 3) / 4, 256, 0, stream>>>(
            row_ptr, src_s, a_src, a_dst, h, conv_b + l * HIDDEN, rc);
        if (l == 0)
            gemmp_k<__hip_bfloat16><<<512, 256, 0, stream>>>(
                rc, pwb + (size_t)l * HIDDEN * HIDDEN,
                xc, swb + (size_t)l * HIDDEN * HIDDEN,
                proj_b + l * HIDDEN, skip_b + l * HIDDEN, xb, mtiles);
        else
            gemmp_k<float><<<512, 256, 0, stream>>>(
                rc, pwb + (size_t)l * HIDDEN * HIDDEN,
                xc, swb + (size_t)l * HIDDEN * HIDDEN,
                proj_b + l * HIDDEN, skip_b + l * HIDDEN, out, mtiles);
        xc = xb;
    }
}

// Round 8
// 359.874 us; speedup vs baseline: 2.6752x; 1.3280x over previous
//
#include <hip/hip_runtime.h>
#include <hip/hip_bf16.h>
#include <stdint.h>

#define N_NODES 50000
#define N_EDGES 800000
#define HIDDEN  128
#define HEADS   4
#define HD      (HEADS*HIDDEN)   // 512
#define CAST_Q  (N_NODES*HIDDEN/4)   // 1,600,000 float4 quads of x

typedef __attribute__((ext_vector_type(8))) short  short8;
typedef __attribute__((ext_vector_type(4))) float  floatx4;
typedef __attribute__((ext_vector_type(2))) float  floatx2;

static __device__ __forceinline__ unsigned short bf16_bits(float f) {
    __hip_bfloat16 h = __float2bfloat16(f);
    union { __hip_bfloat16 b; unsigned short s; } u; u.b = h; return u.s;
}

// leaky_relu(a, 0.2) == max(a, 0.2a); then fast exp
static __device__ __forceinline__ float lexp(float a) {
    return __expf(fmaxf(a, 0.2f * a));
}

// ---------------- fp8 e4m3 encode/decode (HW cvt when available) ----------------

#if __has_builtin(__builtin_amdgcn_cvt_pk_fp8_f32) && __has_builtin(__builtin_amdgcn_cvt_pk_f32_fp8)
#define FP8_HW 1
#else
#define FP8_HW 0
static __device__ __forceinline__ unsigned fp8_enc1(float f) {
    unsigned s = __float_as_uint(f) >> 31;
    float a = fabsf(f);
    if (a < 0.0009765625f) return s << 7;
    if (a > 448.f) a = 448.f;
    unsigned ub = __float_as_uint(a) + 0x00080000u;  // round at bit19
    int e = (int)((ub >> 23) & 255) - 120;           // biased-7 exponent
    unsigned m = (ub >> 20) & 7;
    if (e <= 0) {
        int mm = (int)(a * 512.f + 0.5f); if (mm > 7) mm = 7;
        return (s << 7) | (unsigned)mm;
    }
    if (e > 15) { e = 15; m = 7; }
    return (s << 7) | ((unsigned)e << 3) | m;
}
static __device__ __forceinline__ float fp8_dec1(unsigned b) {
    unsigned s = (b >> 7) & 1, e = (b >> 3) & 15, m = b & 7;
    if (e == 0) { float f = (float)m * 0.001953125f; return s ? -f : f; }
    return __uint_as_float((s << 31) | ((e + 120) << 23) | (m << 20));
}
#endif

static __device__ __forceinline__ unsigned fp8_pack4(float a, float b, float c, float d) {
#if FP8_HW
    int w = __builtin_amdgcn_cvt_pk_fp8_f32(a, b, 0, false);
    w     = __builtin_amdgcn_cvt_pk_fp8_f32(c, d, w, true);
    return (unsigned)w;
#else
    return fp8_enc1(a) | (fp8_enc1(b) << 8) | (fp8_enc1(c) << 16) | (fp8_enc1(d) << 24);
#endif
}

static __device__ __forceinline__ void accf8(float* acc, uint2 u, float wt) {
#if FP8_HW
    floatx2 f;
    f = __builtin_amdgcn_cvt_pk_f32_fp8((int)u.x, false); acc[0] += wt * f.x; acc[1] += wt * f.y;
    f = __builtin_amdgcn_cvt_pk_f32_fp8((int)u.x, true);  acc[2] += wt * f.x; acc[3] += wt * f.y;
    f = __builtin_amdgcn_cvt_pk_f32_fp8((int)u.y, false); acc[4] += wt * f.x; acc[5] += wt * f.y;
    f = __builtin_amdgcn_cvt_pk_f32_fp8((int)u.y, true);  acc[6] += wt * f.x; acc[7] += wt * f.y;
#else
    acc[0] += wt * fp8_dec1(u.x & 255);         acc[1] += wt * fp8_dec1((u.x >> 8) & 255);
    acc[2] += wt * fp8_dec1((u.x >> 16) & 255); acc[3] += wt * fp8_dec1(u.x >> 24);
    acc[4] += wt * fp8_dec1(u.y & 255);         acc[5] += wt * fp8_dec1((u.y >> 8) & 255);
    acc[6] += wt * fp8_dec1((u.y >> 16) & 255); acc[7] += wt * fp8_dec1(u.y >> 24);
#endif
}

// ---------------- prep: x fp32->bf16 cast + weight swizzle, one launch ----------------
// cast part: quads 0..CAST_Q-1.  wswz part: offsets 0..196607.
// fragment element (kc,nt,q,r,j) at offset ((kc*(N/16)+nt)*4+q)*128 + r*8 + j
// natural source row kr = kc*32+q*8+j, col = nt*16+r.
// proj_w rows PERMUTED (kr -> (kr&7)*16 + (kr>>3)) to compensate rc's [r][ntl] layout.

__global__ __launch_bounds__(256) void prep_k(
        const float* __restrict__ x, unsigned short* __restrict__ xb16,
        const float* __restrict__ conv_w, const float* __restrict__ proj_w,
        const float* __restrict__ skip_w,
        unsigned short* __restrict__ cwb, unsigned short* __restrict__ pwb,
        unsigned short* __restrict__ swb) {
    int i = blockIdx.x * 256 + threadIdx.x;
    if (i < CAST_Q) {
        float4 v = ((const float4*)x)[i];
        uint2 p;
        p.x = (unsigned)bf16_bits(v.x) | ((unsigned)bf16_bits(v.y) << 16);
        p.y = (unsigned)bf16_bits(v.z) | ((unsigned)bf16_bits(v.w) << 16);
        ((uint2*)xb16)[i] = p;
        return;
    }
    int o = i - CAST_Q;
    const float* B; unsigned short* D; int off, N; bool perm = false;
    if (o < 131072)      { B = conv_w + (o >> 16) * 65536; D = cwb + (o >> 16) * 65536; off = o & 65535; N = 512; }
    else if (o < 163840) { int t = o - 131072; B = proj_w + (t >> 14) * 16384; D = pwb + (t >> 14) * 16384; off = t & 16383; N = 128; perm = true; }
    else if (o < 196608) { int t = o - 163840; B = skip_w + (t >> 14) * 16384; D = swb + (t >> 14) * 16384; off = t & 16383; N = 128; }
    else return;
    int j = off & 7, r = (off >> 3) & 15, q = (off >> 7) & 3;
    int rest = off >> 9, ntn = N >> 4;
    int nt = rest % ntn, kc = rest / ntn;
    int kr = kc * 32 + q * 8 + j;
    int row = perm ? ((kr & 7) * 16 + (kr >> 3)) : kr;
    D[off] = bf16_bits(B[(size_t)row * N + nt * 16 + r]);
}

// ---------------- CSR build ----------------

__global__ __launch_bounds__(256) void hist_k(const int* __restrict__ dst,
                                              int* __restrict__ cnt, int E) {
    int e = blockIdx.x * 256 + threadIdx.x;
    if (e < E) atomicAdd(&cnt[dst[e]], 1);
}

__global__ __launch_bounds__(1024) void scan1_k(const int* __restrict__ cnt,
                                                int* __restrict__ row_ptr,
                                                int* __restrict__ bsum, int n) {
    __shared__ int buf[1024];
    int t = threadIdx.x, i = blockIdx.x * 1024 + t;
    int v = (i < n) ? cnt[i] : 0;
    buf[t] = v;
    __syncthreads();
    for (int off = 1; off < 1024; off <<= 1) {
        int xv = (t >= off) ? buf[t - off] : 0;
        __syncthreads();
        buf[t] += xv;
        __syncthreads();
    }
    if (i < n) row_ptr[i] = buf[t] - v;
    if (t == 1023) bsum[blockIdx.x] = buf[1023];
}

__global__ void scan2_k(int* __restrict__ bsum, int nb) {
    if (threadIdx.x == 0) {
        int acc = 0;
        for (int i = 0; i < nb; ++i) { int v = bsum[i]; bsum[i] = acc; acc += v; }
    }
}

__global__ __launch_bounds__(1024) void scan3_k(int* __restrict__ row_ptr,
                                                const int* __restrict__ bsum, int n, int E) {
    int i = blockIdx.x * 1024 + threadIdx.x;
    if (i < n) row_ptr[i] += bsum[blockIdx.x];
    if (i == 0) row_ptr[n] = E;
}

__global__ __launch_bounds__(256) void scatter_k(const int* __restrict__ src,
                                                 const int* __restrict__ dst,
                                                 const int* __restrict__ row_ptr,
                                                 int* __restrict__ fill,
                                                 int* __restrict__ src_sorted, int E) {
    int e = blockIdx.x * 256 + threadIdx.x;
    if (e >= E) return;
    int d = dst[e];
    int p = row_ptr[d] + atomicAdd(&fill[d], 1);
    src_sorted[p] = src[e];
}

// ---------------- conv GEMM: h8 = fp8(A@conv_w), B-in-registers, fused alpha ----------------
// h8 row layout (bytes): [head][r][ntl]; natural channel ntl*16+r at byte r*8+ntl of head slice.

__global__ __launch_bounds__(256, 2) void gemmc_k(
        const __hip_bfloat16* __restrict__ A,      // M x 128 bf16 (natural)
        const unsigned short* __restrict__ Bs,     // swizzled 128x512
        const float* __restrict__ att_s, const float* __restrict__ att_d,
        unsigned char* __restrict__ h8,
        float* __restrict__ a_src, float* __restrict__ a_dst, int mtiles) {
    int head = threadIdx.x >> 6;
    int lane = threadIdx.x & 63;
    int r = lane & 15, q = lane >> 4;

    short8 Bf[4][8];
#pragma unroll
    for (int kc = 0; kc < 4; ++kc)
#pragma unroll
        for (int ntl = 0; ntl < 8; ++ntl)
            Bf[kc][ntl] = *(const short8*)((const short*)Bs +
                (((size_t)(kc * 32 + head * 8 + ntl) * 4 + q) * 128 + r * 8));

    float as_r[8], ad_r[8];
#pragma unroll
    for (int ntl = 0; ntl < 8; ++ntl) {
        as_r[ntl] = att_s[head * HIDDEN + ntl * 16 + r];
        ad_r[ntl] = att_d[head * HIDDEN + ntl * 16 + r];
    }

    for (int mt = blockIdx.x; mt < mtiles; mt += gridDim.x) {
        int m0 = mt * 16;
        const short* Ab = (const short*)A + (size_t)(m0 + r) * HIDDEN + q * 8;
        short8 av[4];
#pragma unroll
        for (int kc = 0; kc < 4; ++kc) av[kc] = *(const short8*)(Ab + kc * 32);

        floatx4 acc[8];
#pragma unroll
        for (int i = 0; i < 8; ++i) acc[i] = (floatx4){0.f, 0.f, 0.f, 0.f};
#pragma unroll
        for (int kc = 0; kc < 4; ++kc)
#pragma unroll
            for (int ntl = 0; ntl < 8; ++ntl)
                acc[ntl] = __builtin_amdgcn_mfma_f32_16x16x32_bf16(av[kc], Bf[kc][ntl], acc[ntl], 0, 0, 0);

        // store h8: row q*4+i, 8 B per row per lane
#pragma unroll
        for (int i = 0; i < 4; ++i) {
            uint2 o;
            o.x = fp8_pack4(acc[0][i], acc[1][i], acc[2][i], acc[3][i]);
            o.y = fp8_pack4(acc[4][i], acc[5][i], acc[6][i], acc[7][i]);
            *(uint2*)(h8 + (size_t)(m0 + q * 4 + i) * HD + head * HIDDEN + r * 8) = o;
        }
        // fused alpha (fp32 accumulators — full precision)
        float sA[4] = {0, 0, 0, 0}, sD[4] = {0, 0, 0, 0};
#pragma unroll
        for (int ntl = 0; ntl < 8; ++ntl)
#pragma unroll
            for (int i = 0; i < 4; ++i) {
                sA[i] += acc[ntl][i] * as_r[ntl];
                sD[i] += acc[ntl][i] * ad_r[ntl];
            }
#pragma unroll
        for (int d = 1; d < 16; d <<= 1)
#pragma unroll
            for (int i = 0; i < 4; ++i) {
                sA[i] += __shfl_xor(sA[i], d);
                sD[i] += __shfl_xor(sD[i], d);
            }
        if (r == 0)
#pragma unroll
            for (int i = 0; i < 4; ++i) {
                int row = m0 + q * 4 + i;
                a_src[row * HEADS + head] = sA[i];
                a_dst[row * HEADS + head] = sD[i];
            }
    }
}

// ---------------- proj+skip dual GEMM: B-in-registers, grid-stride M ----------------

template <typename OutT>
__global__ __launch_bounds__(256, 2) void gemmp_k(
        const __hip_bfloat16* __restrict__ A,  const unsigned short* __restrict__ Bs,
        const __hip_bfloat16* __restrict__ A2, const unsigned short* __restrict__ Bs2,
        const float* __restrict__ b1, const float* __restrict__ b2,
        OutT* __restrict__ D, int mtiles) {
    int wave = threadIdx.x >> 6;
    int lane = threadIdx.x & 63;
    int r = lane & 15, q = lane >> 4;
    int nh = wave & 1;

    short8 Bf[4][4], Bf2[4][4];
#pragma unroll
    for (int kc = 0; kc < 4; ++kc)
#pragma unroll
        for (int ntl = 0; ntl < 4; ++ntl) {
            size_t off = (((size_t)(kc * 8 + nh * 4 + ntl) * 4 + q) * 128 + r * 8);
            Bf[kc][ntl]  = *(const short8*)((const short*)Bs  + off);
            Bf2[kc][ntl] = *(const short8*)((const short*)Bs2 + off);
        }
    float bias[4];
#pragma unroll
    for (int ntl = 0; ntl < 4; ++ntl) {
        int col = nh * 64 + ntl * 16 + r;
        bias[ntl] = b1[col] + b2[col];
    }

    for (int mt = blockIdx.x * 2 + (wave >> 1); mt < mtiles; mt += gridDim.x * 2) {
        int m0 = mt * 16;
        const short* Ab  = (const short*)A  + (size_t)(m0 + r) * HIDDEN + q * 8;
        const short* Ab2 = (const short*)A2 + (size_t)(m0 + r) * HIDDEN + q * 8;
        short8 av[4], av2[4];
#pragma unroll
        for (int kc = 0; kc < 4; ++kc) {
            av[kc]  = *(const short8*)(Ab  + kc * 32);
            av2[kc] = *(const short8*)(Ab2 + kc * 32);
        }
        floatx4 acc[4];
#pragma unroll
        for (int i = 0; i < 4; ++i) acc[i] = (floatx4){0.f, 0.f, 0.f, 0.f};
#pragma unroll
        for (int kc = 0; kc < 4; ++kc)
#pragma unroll
            for (int ntl = 0; ntl < 4; ++ntl) {
                acc[ntl] = __builtin_amdgcn_mfma_f32_16x16x32_bf16(av[kc],  Bf[kc][ntl],  acc[ntl], 0, 0, 0);
                acc[ntl] = __builtin_amdgcn_mfma_f32_16x16x32_bf16(av2[kc], Bf2[kc][ntl], acc[ntl], 0, 0, 0);
            }
#pragma unroll
        for (int ntl = 0; ntl < 4; ++ntl) {
            int col = nh * 64 + ntl * 16 + r;
#pragma unroll
            for (int i = 0; i < 4; ++i) {
                int row = m0 + q * 4 + i;
                float v = acc[ntl][i] + bias[ntl];
                if constexpr (sizeof(OutT) == 4)
                    ((float*)D)[(size_t)row * HIDDEN + col] = v;
                else
                    ((__hip_bfloat16*)D)[(size_t)row * HIDDEN + col] = __float2bfloat16(v);
            }
        }
    }
}

// ---------------- fused softmax + aggregation: one wave per node, fp8 h ----------------

__global__ __launch_bounds__(256) void msg_k(const int* __restrict__ row_ptr,
                                             const int* __restrict__ src_sorted,
                                             const float* __restrict__ a_src,
                                             const float* __restrict__ a_dst,
                                             const unsigned char* __restrict__ h8,
                                             const float* __restrict__ conv_b,
                                             __hip_bfloat16* __restrict__ rc) {
    int wave = threadIdx.x >> 6;
    int lane = threadIdx.x & 63;
    int n = blockIdx.x * 4 + wave;
    if (n >= N_NODES) return;
    int head = lane >> 4;
    float adn = a_dst[n * HEADS + head];
    int beg = row_ptr[n], end = row_ptr[n + 1];
    const uint2* hq = (const uint2*)h8;

    float acc[8] = {0.f, 0.f, 0.f, 0.f, 0.f, 0.f, 0.f, 0.f};
    float esum = 0.f;
    for (int base = beg; base < end; base += 32) {
        int m = min(32, end - base);
        int sv = (lane < m) ? src_sorted[base + lane] : 0;
        int j = 0;
        for (; j + 4 <= m; j += 4) {
            int s0 = __shfl(sv, j),     s1 = __shfl(sv, j + 1);
            int s2 = __shfl(sv, j + 2), s3 = __shfl(sv, j + 3);
            uint2 u0 = hq[(size_t)s0 * 64 + lane];
            uint2 u1 = hq[(size_t)s1 * 64 + lane];
            uint2 u2 = hq[(size_t)s2 * 64 + lane];
            uint2 u3 = hq[(size_t)s3 * 64 + lane];
            float e0 = lexp(a_src[s0 * 4 + head] + adn);
            float e1 = lexp(a_src[s1 * 4 + head] + adn);
            float e2 = lexp(a_src[s2 * 4 + head] + adn);
            float e3 = lexp(a_src[s3 * 4 + head] + adn);
            accf8(acc, u0, e0);
            accf8(acc, u1, e1);
            accf8(acc, u2, e2);
            accf8(acc, u3, e3);
            esum += (e0 + e1) + (e2 + e3);
        }
        for (; j < m; ++j) {
            int s0 = __shfl(sv, j);
            uint2 u0 = hq[(size_t)s0 * 64 + lane];
            float e0 = lexp(a_src[s0 * 4 + head] + adn);
            accf8(acc, u0, e0);
            esum += e0;
        }
    }
    float rinv = 1.f / (esum + 1e-16f);
#pragma unroll
    for (int k = 0; k < 8; ++k) acc[k] *= rinv;
#pragma unroll
    for (int k = 0; k < 8; ++k) {
        acc[k] += __shfl_xor(acc[k], 16);
        acc[k] += __shfl_xor(acc[k], 32);
    }
    if (lane < 16) {
        // lane holds natural channels {k*16+lane}; rc written permuted [r][ntl]
        union { uint4 v; unsigned short us[8]; } o;
#pragma unroll
        for (int k = 0; k < 8; ++k) {
            float mres = 0.25f * acc[k] + conv_b[k * 16 + lane];
            o.us[k] = bf16_bits(mres > 0.f ? mres : 0.f);
        }
        ((uint4*)rc)[(size_t)n * 16 + lane] = o.v;
    }
}

// ---------------- launcher ----------------

extern "C" void kernel_launch(void* const* d_in, const int* in_sizes, int n_in,
                              void* d_out, int out_size, void* d_ws, size_t ws_size,
                              hipStream_t stream) {
    const float* x      = (const float*)d_in[0];
    const int*   ei     = (const int*)d_in[1];
    const float* conv_w = (const float*)d_in[2];
    const float* att_s  = (const float*)d_in[3];
    const float* att_d  = (const float*)d_in[4];
    const float* conv_b = (const float*)d_in[5];
    const float* proj_w = (const float*)d_in[6];
    const float* proj_b = (const float*)d_in[7];
    const float* skip_w = (const float*)d_in[8];
    const float* skip_b = (const float*)d_in[9];
    float* out = (float*)d_out;

    char* ws = (char*)d_ws;
    size_t o = 0;
    auto alloc = [&](size_t b) { size_t c = o; o += (b + 255) & ~(size_t)255; return c; };
    __hip_bfloat16* xb16 = (__hip_bfloat16*)(ws + alloc((size_t)N_NODES * HIDDEN * 2));
    unsigned short* cwb  = (unsigned short*)(ws + alloc((size_t)2 * HIDDEN * HD * 2));
    unsigned short* pwb  = (unsigned short*)(ws + alloc((size_t)2 * HIDDEN * HIDDEN * 2));
    unsigned short* swb  = (unsigned short*)(ws + alloc((size_t)2 * HIDDEN * HIDDEN * 2));
    unsigned char* h8    = (unsigned char*)(ws + alloc((size_t)N_NODES * HD));
    float* a_src         = (float*)(ws + alloc((size_t)N_NODES * HEADS * 4));
    float* a_dst         = (float*)(ws + alloc((size_t)N_NODES * HEADS * 4));
    int* row_ptr         = (int*)(ws + alloc((size_t)(N_NODES + 1) * 4));
    int* cntfill         = (int*)(ws + alloc((size_t)2 * N_NODES * 4));
    int* cnt  = cntfill;
    int* fill = cntfill + N_NODES;
    int* src_s           = (int*)(ws + alloc((size_t)N_EDGES * 4));
    __hip_bfloat16* rc   = (__hip_bfloat16*)(ws + alloc((size_t)N_NODES * HIDDEN * 2));
    __hip_bfloat16* xb   = (__hip_bfloat16*)(ws + alloc((size_t)N_NODES * HIDDEN * 2));
    int* bsum            = (int*)(ws + alloc(64 * 4));

    const int* srcp = ei;
    const int* dstp = ei + N_EDGES;

    (void)hipMemsetAsync(cntfill, 0, (size_t)2 * N_NODES * 4, stream);

    prep_k<<<(CAST_Q + 196608 + 255) / 256, 256, 0, stream>>>(
        x, (unsigned short*)xb16, conv_w, proj_w, skip_w, cwb, pwb, swb);

    hist_k<<<(N_EDGES + 255) / 256, 256, 0, stream>>>(dstp, cnt, N_EDGES);
    const int nb = (N_NODES + 1023) / 1024;  // 49
    scan1_k<<<nb, 1024, 0, stream>>>(cnt, row_ptr, bsum, N_NODES);
    scan2_k<<<1, 64, 0, stream>>>(bsum, nb);
    scan3_k<<<nb, 1024, 0, stream>>>(row_ptr, bsum, N_NODES, N_EDGES);
    scatter_k<<<(N_EDGES + 255) / 256, 256, 0, stream>>>(srcp, dstp, row_ptr, fill, src_s, N_EDGES);

    const int mtiles = N_NODES / 16;          // 3125 (exact)
    const __hip_bfloat16* xc = xb16;
    for (int l = 0; l < 2; ++l) {
        gemmc_k<<<512, 256, 0, stream>>>(
            xc, cwb + (size_t)l * HIDDEN * HD,
            att_s + l * HD, att_d + l * HD, h8, a_src, a_dst, mtiles);
        msg_k<<<(N_NODES + 3) / 4, 256, 0, stream>>>(
            row_ptr, src_s, a_src, a_dst, h8, conv_b + l * HIDDEN, rc);
        if (l == 0)
            gemmp_k<__hip_bfloat16><<<512, 256, 0, stream>>>(
                rc, pwb + (size_t)l * HIDDEN * HIDDEN,
                xc, swb + (size_t)l * HIDDEN * HIDDEN,
                proj_b + l * HIDDEN, skip_b + l * HIDDEN, xb, mtiles);
        else
            gemmp_k<float><<<512, 256, 0, stream>>>(
                rc, pwb + (size_t)l * HIDDEN * HIDDEN,
                xc, swb + (size_t)l * HIDDEN * HIDDEN,
                proj_b + l * HIDDEN, skip_b + l * HIDDEN, out, mtiles);
        xc = xb;
    }
}